// Round 9
// baseline (1488.328 us; speedup 1.0000x reference)
//
#include <hip/hip_runtime.h>
#include <math.h>

// FNO2D: B=16, H=W=256, C_IN=C_OUT=2, WIDTH=64, MODES=16, NLAYERS=4
// Partial DFTs (32 kx rows x 16 ky cols). Batch in 2 chunks of CB=8.
// h stored as TWO bf16 planes (hi+lo, exact split of fp32).
// Fused layer kernel: per-lane register IDFT-H -> B-frags (no LDS-B),
// reg-prefetched h staging, conv+IDFT-W MFMA, gelu, DFT-W MFMA -> Y1.

#define CB 8   // batch chunk size

typedef __attribute__((ext_vector_type(8))) __bf16 bf16x8;
typedef __attribute__((ext_vector_type(4))) float f32x4;

// ---- workspace layout (float offsets), per batch chunk ----
static const long long SZ_HC    = (long long)CB*256*256*64;  // 33,554,432 floats region
static const long long OFF_HLO_F= SZ_HC/2;                   // hi plane: ws[0..), lo plane as ushort
static const long long SZ_Y1C   = (long long)CB*16*256*64;   // 2,097,152 per plane
static const long long OFF_Y1RE = SZ_HC;
static const long long OFF_Y1IM = OFF_Y1RE + SZ_Y1C;
static const long long SZ_FTC   = (long long)CB*32*16*64;    // 262,144 per plane
static const long long OFF_FTRE = OFF_Y1RE + 2*SZ_Y1C;
static const long long OFF_FTIM = OFF_FTRE + SZ_FTC;
static const long long OFF_O2   = OFF_FTRE + 2*SZ_FTC;       // O interleaved float2 [b][kxi][ky][o]
static const long long SZ_WT    = 4LL*32*16*64*64;           // 8,388,608 per plane
static const long long OFF_WTRE = OFF_FTRE + 4*SZ_FTC;
static const long long OFF_WTIM = OFF_WTRE + SZ_WT;
static const long long OFF_CWT  = OFF_WTIM + SZ_WT;          // legacy slot
static const long long OFF_FW   = OFF_CWT + 4LL*64*64;       // legacy slot
static const long long OFF_TW   = OFF_FW + 256LL*32;         // float2[256] (cos,sin)
static const long long OFF_TWA  = OFF_TW + 512;              // layer_out IDFT-W A frags (hi+lo)
static const long long OFF_CWB  = OFF_TWA + 8192;            // cw bf16 hi+lo
static const long long OFF_FWA  = OFF_CWB + 16384;           // dftw F A-frags hi+lo
static const long long OFF_P1T  = OFF_FWA + 8192;            // p1^T bf16 hi+lo
static const long long WS_FLOATS= OFF_P1T + 8192;            // ~212 MB

#define C2PI 0.0245436926061702596f
#define GELU(v) (0.5f*(v)*(1.0f + erff((v)*0.70710678118654752f)))

__device__ __forceinline__ void split2(float v, ushort& hi, ushort& lo) {
    unsigned u = __float_as_uint(v);
    hi = (ushort)(u >> 16);
    float fhi = __uint_as_float(u & 0xffff0000u);
    float r = v - fhi;
    lo = (ushort)(__float_as_uint(r) >> 16);
}

union U8 { ushort u[8]; uint4 v; };
union U4 { ushort u[4]; uint2 v; };

// ---- tables: TW, layer_out A-frags (TWA), dftw A-frags (FWA) ----
__global__ void k_init_tables(float* ws) {
    int t = threadIdx.x;
    float ang = (float)t * C2PI;
    float s, c;
    sincosf(ang, &s, &c);
    ((float2*)(ws + OFF_TW))[t] = make_float2(c, s);
    // TWA: layer_out A (rows w, K=kk): w = wt*16+(lane&15), kk = 8*(lane>>4)+j
    ushort* twh = (ushort*)(ws + OFF_TWA);
    ushort* twl = twh + 8192;
    int lidx = t & 63;
    int quarter = t >> 6;
    for (int wt = 0; wt < 16; wt++) {
        for (int jq = 0; jq < 2; jq++) {
            int j = quarter*2 + jq;
            int w = wt*16 + (lidx & 15);
            int kk = 8*(lidx >> 4) + j;
            int ky = kk >> 1;
            float a2 = (float)((ky * w) & 255) * C2PI;
            float ss, cc; sincosf(a2, &ss, &cc);
            float val = (kk & 1) ? -ss : cc;
            ushort hi, lo; split2(val, hi, lo);
            twh[(wt*64 + lidx)*8 + j] = hi;
            twl[(wt*64 + lidx)*8 + j] = lo;
        }
    }
    // FWA: dftw A (rows kk, K=w): kk = mt*16+(lane&15), w = ks*32+8*(lane>>4)+j
    ushort* fh = (ushort*)(ws + OFF_FWA);
    ushort* fl = fh + 8192;
    for (int n = t; n < 8192; n += 256) {
        int j = n & 7, ln = (n >> 3) & 63, ks = (n >> 9) & 7, mt2 = n >> 12;
        int kk = mt2*16 + (ln & 15);
        int w = ks*32 + 8*(ln >> 4) + j;
        int ky = kk >> 1;
        float a2 = (float)((ky * w) & 255) * C2PI;
        float ss, cc; sincosf(a2, &ss, &cc);
        float val = (kk & 1) ? -ss : cc;
        ushort hi, lo; split2(val, hi, lo);
        fh[n] = hi; fl[n] = lo;
    }
}

// ---- weight transpose: [l][i][o][x][ky] -> [l][kxi][ky][i][o] ----
__global__ __launch_bounds__(256) void k_wtrans(const float* w1r, const float* w1i,
                                                const float* w2r, const float* w2i,
                                                float* ws) {
    __shared__ float s_t[128*65];
    int t = threadIdx.x;
    int bid = blockIdx.x;                 // 2048 blocks
    int p    = bid & 1;
    int mh   = (bid >> 1) & 1;
    int tsel = (bid >> 2) & 1;
    int i    = (bid >> 3) & 63;
    int l    = bid >> 9;
    const float* src = tsel == 0 ? (p ? w1i : w1r) : (p ? w2i : w2r);
    const float* srcbase = src + ((long long)(l*64 + i)*64)*256;
    int msub = mh*128;
    for (int j = 0; j < 8; j++) {
        int n = j*256 + t;
        int o = n >> 5, mf4 = n & 31;
        float4 v = *(const float4*)(srcbase + o*256 + msub + mf4*4);
        int m0 = mf4*4;
        s_t[(m0+0)*65 + o] = v.x;
        s_t[(m0+1)*65 + o] = v.y;
        s_t[(m0+2)*65 + o] = v.z;
        s_t[(m0+3)*65 + o] = v.w;
    }
    __syncthreads();
    float* dst = ws + (p ? OFF_WTIM : OFF_WTRE);
    int o4 = t & 15, mq = t >> 4;
    for (int it = 0; it < 8; it++) {
        int ml = it*16 + mq;
        float4 w = make_float4(s_t[ml*65 + o4*4 + 0], s_t[ml*65 + o4*4 + 1],
                               s_t[ml*65 + o4*4 + 2], s_t[ml*65 + o4*4 + 3]);
        long long idx = ((long long)(l*512 + tsel*256 + msub + ml))*4096 + i*64 + o4*4;
        *(float4*)(dst + idx) = w;
    }
}

// ---- cw -> bf16 hi/lo planes [l][o][i] ----
__global__ void k_cwtrans(const float* cw, float* ws) {
    int gid = blockIdx.x * 256 + threadIdx.x;  // 16384
    ushort* ch = (ushort*)(ws + OFF_CWB);
    ushort* cl = ch + 16384;
    ushort hi, lo; split2(cw[gid], hi, lo);
    ch[gid] = hi; cl[gid] = lo;
}

// ---- p1 transpose -> bf16 hi/lo planes p1t[u(128)][i(64)] ----
__global__ void k_p1trans(const float* p1w, float* ws) {
    int gid = blockIdx.x * 256 + threadIdx.x;  // 8192
    int u = gid >> 6, i = gid & 63;
    ushort* ph = (ushort*)(ws + OFF_P1T);
    ushort hi, lo; split2(p1w[i*128 + u], hi, lo);
    ph[gid] = hi; ph[8192 + gid] = lo;
}

// ---- lift: h = x@lw + lb, split to hi/lo planes ----
__global__ __launch_bounds__(256) void k_lift(const float* x, const float* lw,
                                              const float* lb, float* ws, int bbase) {
    long long gid8 = (long long)blockIdx.x * 256 + threadIdx.x;  // < CB*65536*8
    int c0 = (int)(gid8 & 7) * 8;
    long long pixl = gid8 >> 3;
    const float* xp = x + ((long long)bbase*65536 + pixl)*2;
    float x0 = xp[0], x1 = xp[1];
    U8 hi, lo;
    #pragma unroll
    for (int j = 0; j < 8; j++) {
        int c = c0 + j;
        float v = x0*lw[c] + x1*lw[64 + c] + lb[c];
        split2(v, hi.u[j], lo.u[j]);
    }
    ushort* hH = (ushort*)ws;
    ushort* hL = (ushort*)(ws + OFF_HLO_F);
    *(uint4*)&hH[pixl*64 + c0] = hi.v;
    *(uint4*)&hL[pixl*64 + c0] = lo.v;
}

// ---- chunk-initial DFT-W via MFMA: Y1[kk(32) x c(64)] = F[32x256]@h[256x64] ----
__global__ __launch_bounds__(256) void k_dftw(float* ws) {
    __shared__ ushort sBhi[64*128];
    __shared__ ushort sBlo[64*128];
    int t = threadIdx.x;
    int bh = blockIdx.x;                  // CB*256
    int lane = t & 63, wid = t >> 6;
    int oc = lane & 15, g = lane >> 4;
    const ushort* hH = (const ushort*)ws;
    const ushort* hL = (const ushort*)(ws + OFF_HLO_F);
    const ushort* fh = (const ushort*)(ws + OFF_FWA);
    const ushort* fl = fh + 8192;
    int mt = wid & 1, nt0 = wid >> 1;
    f32x4 acc0 = {0.f,0.f,0.f,0.f}, acc1 = {0.f,0.f,0.f,0.f};
    long long rowbase = (long long)bh * 16384;
    for (int half = 0; half < 2; half++) {
        __syncthreads();
        for (int r = 0; r < 2; r++) {
            int n = r*256 + t;            // 0..511
            int c0 = (n & 7) * 8;
            int w = (n >> 3) * 2;         // 0..126
            long long gidx = rowbase + (long long)(half*128 + w)*64 + c0;
            U8 a, b2;
            a.v  = *(const uint4*)&hH[gidx];
            b2.v = *(const uint4*)&hH[gidx + 64];
            #pragma unroll
            for (int j = 0; j < 8; j++) {
                int c = c0 + j;
                int key = (((c & 7) ^ ((c >> 3) & 7)) << 3);
                *(uint*)&sBhi[c*128 + (w ^ key)] = (uint)a.u[j] | ((uint)b2.u[j] << 16);
            }
            a.v  = *(const uint4*)&hL[gidx];
            b2.v = *(const uint4*)&hL[gidx + 64];
            #pragma unroll
            for (int j = 0; j < 8; j++) {
                int c = c0 + j;
                int key = (((c & 7) ^ ((c >> 3) & 7)) << 3);
                *(uint*)&sBlo[c*128 + (w ^ key)] = (uint)a.u[j] | ((uint)b2.u[j] << 16);
            }
        }
        __syncthreads();
        #pragma unroll
        for (int ksl = 0; ksl < 4; ksl++) {
            int gks = half*4 + ksl;
            bf16x8 Ah = *(const bf16x8*)&fh[((mt*8 + gks)*64 + lane)*8];
            bf16x8 Al = *(const bf16x8*)&fl[((mt*8 + gks)*64 + lane)*8];
            int wof = ksl*32 + 8*g;
            #pragma unroll
            for (int q = 0; q < 2; q++) {
                int c = (nt0 + q*2)*16 + oc;
                int key = (((c & 7) ^ ((c >> 3) & 7)) << 3);
                bf16x8 Bh = *(const bf16x8*)&sBhi[c*128 + (wof ^ key)];
                bf16x8 Bl = *(const bf16x8*)&sBlo[c*128 + (wof ^ key)];
                f32x4 a = q ? acc1 : acc0;
                a = __builtin_amdgcn_mfma_f32_16x16x32_bf16(Ah, Bh, a, 0,0,0);
                a = __builtin_amdgcn_mfma_f32_16x16x32_bf16(Al, Bh, a, 0,0,0);
                a = __builtin_amdgcn_mfma_f32_16x16x32_bf16(Ah, Bl, a, 0,0,0);
                if (q) acc1 = a; else acc0 = a;
            }
        }
    }
    int b = bh >> 8, hh = bh & 255;
    #pragma unroll
    for (int q = 0; q < 2; q++) {
        f32x4 a = q ? acc1 : acc0;
        int c = (nt0 + q*2)*16 + oc;
        #pragma unroll
        for (int r = 0; r < 4; r++) {
            int kk = mt*16 + 4*g + r;
            int ky = kk >> 1;
            long long addr = ((long long)(b*16 + ky)*256 + hh)*64 + c;
            ws[((kk & 1) ? OFF_Y1IM : OFF_Y1RE) + addr] = a[r];
        }
    }
}

// ---- DFT along H (fp32 VALU) ----
__global__ __launch_bounds__(256) void k_dfth(float* ws) {
    __shared__ __align__(16) float s_yre[64*32];
    __shared__ __align__(16) float s_yim[64*32];
    __shared__ __align__(16) float s_tw[512];
    int t = threadIdx.x;
    int bk = blockIdx.x;
    int chalf = bk & 1;
    int ky = (bk >> 1) & 15;
    int b = bk >> 5;
    ((float2*)s_tw)[t] = ((const float2*)(ws + OFF_TW))[t];
    int kxi = t & 31;
    int cq = t >> 5;
    int kxa = (kxi < 16) ? kxi : (224 + kxi);
    float accRe[4] = {0.f,0.f,0.f,0.f}, accIm[4] = {0.f,0.f,0.f,0.f};
    const float* yre = ws + OFF_Y1RE + (long long)(b*16 + ky)*(256*64);
    const float* yim = ws + OFF_Y1IM + (long long)(b*16 + ky)*(256*64);
    for (int chunk = 0; chunk < 4; chunk++) {
        __syncthreads();
        for (int j = 0; j < 2; j++) {
            int n = j*256 + t;
            int hl = n >> 3, c4 = n & 7;
            long long soff = (long long)(chunk*64 + hl)*64 + chalf*32 + c4*4;
            ((float4*)s_yre)[hl*8 + c4] = *(const float4*)(yre + soff);
            ((float4*)s_yim)[hl*8 + c4] = *(const float4*)(yim + soff);
        }
        __syncthreads();
        for (int hl = 0; hl < 64; hl++) {
            int h = chunk*64 + hl;
            float2 tw = ((const float2*)s_tw)[(kxa*h) & 255];
            float4 yr = *(const float4*)&s_yre[hl*32 + 4*cq];
            float4 yi = *(const float4*)&s_yim[hl*32 + 4*cq];
            accRe[0] += yr.x*tw.x + yi.x*tw.y;
            accRe[1] += yr.y*tw.x + yi.y*tw.y;
            accRe[2] += yr.z*tw.x + yi.z*tw.y;
            accRe[3] += yr.w*tw.x + yi.w*tw.y;
            accIm[0] += yi.x*tw.x - yr.x*tw.y;
            accIm[1] += yi.y*tw.x - yr.y*tw.y;
            accIm[2] += yi.z*tw.x - yr.z*tw.y;
            accIm[3] += yi.w*tw.x - yr.w*tw.y;
        }
    }
    long long base = ((long long)((b*32 + kxi)*16 + ky))*64 + chalf*32 + 4*cq;
    *(float4*)&ws[OFF_FTRE + base] = make_float4(accRe[0], accRe[1], accRe[2], accRe[3]);
    *(float4*)&ws[OFF_FTIM + base] = make_float4(accIm[0], accIm[1], accIm[2], accIm[3]);
}

// ---- mode mix: writes O interleaved float2 [b][kxi][ky][o] ----
__global__ __launch_bounds__(256) void k_mix(float* ws, int l) {
    __shared__ __align__(16) float2 s_ft[CB*64];
    int t = threadIdx.x;
    int kk = blockIdx.x;
    int kxi = kk >> 4, ky = kk & 15;
    for (int j = 0; j < 2; j++) {
        int idx = j*256 + t;
        int i = idx & 63, b = idx >> 6;
        long long a = ((long long)(b*32 + kxi)*16 + ky)*64 + i;
        s_ft[b*64 + i] = make_float2(ws[OFF_FTRE + a], ws[OFF_FTIM + a]);
    }
    __syncthreads();
    int o = t & 63, bq = t >> 6;
    const float* wr = ws + OFF_WTRE + (((long long)l*32 + kxi)*16 + ky)*4096;
    const float* wi = ws + OFF_WTIM + (((long long)l*32 + kxi)*16 + ky)*4096;
    float accRe[2] = {0.f,0.f}, accIm[2] = {0.f,0.f};
    #pragma unroll 4
    for (int i = 0; i < 64; i++) {
        float wrv = wr[i*64 + o], wiv = wi[i*64 + o];
        #pragma unroll
        for (int j = 0; j < 2; j++) {
            float2 a = s_ft[(bq*2 + j)*64 + i];
            accRe[j] += a.x*wrv - a.y*wiv;
            accIm[j] += a.x*wiv + a.y*wrv;
        }
    }
    #pragma unroll
    for (int j = 0; j < 2; j++) {
        int b = bq*2 + j;
        long long a = ((long long)(b*32 + kxi)*16 + ky)*64 + o;
        ((float2*)(ws + OFF_O2))[a] = make_float2(accRe[j], accIm[j]);
    }
}

// ---- fused layer: reg-IDFT-H -> B-frags; conv+IDFT-W MFMA; gelu; DFT-W -> Y1 ----
__global__ __launch_bounds__(256) void k_layer_out(float* ws, const float* cb, int l, int do_dft) {
    __shared__ __align__(16) ushort sMem[16384];   // 32 KB: sA / sT union
    ushort* sAhi = sMem;          // h_old staging 128*64 (swizzled)
    ushort* sAlo = sMem + 8192;
    ushort* sThi = sMem;          // h_new transposed 64*128 (swizzled)
    ushort* sTlo = sMem + 8192;
    int t = threadIdx.x;
    int bh = blockIdx.x;
    int lane = t & 63, wid = t >> 6;
    int oc = lane & 15, g = lane >> 4;
    int b = bh >> 8, hh = bh & 255;
    ushort* hH = (ushort*)ws;
    ushort* hL = (ushort*)(ws + OFF_HLO_F);
    long long rowbase = (long long)bh * 16384;
    int o = wid*16 + oc;

    // ---- issue half-0 staging loads into registers ----
    uint4 stH[4], stL[4];
    int sidx[4];
    {
        const ushort* srcH = hH + rowbase;
        const ushort* srcL = hL + rowbase;
        #pragma unroll
        for (int r = 0; r < 4; r++) {
            int n = r*256 + t;
            int row = n >> 3, i0 = (n & 7)*8;
            stH[r] = *(const uint4*)&srcH[row*64 + i0];
            stL[r] = *(const uint4*)&srcL[row*64 + i0];
            sidx[r] = row*64 + (i0 ^ ((row & 7) << 3));
        }
    }
    // ---- B-frags in registers: g-part via per-lane IDFT-H (k=0..31) ----
    bf16x8 B_h[3], B_l[3];
    {
        const float2* o2 = (const float2*)(ws + OFF_O2);
        const float2* twg = (const float2*)(ws + OFF_TW);
        float gr[4] = {0.f,0.f,0.f,0.f}, gi[4] = {0.f,0.f,0.f,0.f};
        for (int kxi = 0; kxi < 32; kxi++) {
            int kxa = (kxi < 16) ? kxi : (224 + kxi);
            float2 tw = twg[(kxa * hh) & 255];
            long long a = ((long long)((b*32 + kxi)*16 + 4*g))*64 + o;
            #pragma unroll
            for (int kyi = 0; kyi < 4; kyi++) {
                float2 v = o2[a + kyi*64];
                gr[kyi] += v.x*tw.x - v.y*tw.y;
                gi[kyi] += v.x*tw.y + v.y*tw.x;
            }
        }
        U8 bh8, bl8;
        #pragma unroll
        for (int kyi = 0; kyi < 4; kyi++) {
            float scale = (g == 0 && kyi == 0) ? (1.0f/65536.0f) : (2.0f/65536.0f);
            split2(gr[kyi]*scale, bh8.u[2*kyi],   bl8.u[2*kyi]);
            split2(gi[kyi]*scale, bh8.u[2*kyi+1], bl8.u[2*kyi+1]);
        }
        B_h[0] = *(bf16x8*)&bh8; B_l[0] = *(bf16x8*)&bl8;
        // cw part (k=32..95) straight from global (L2-hot)
        const ushort* ch = (const ushort*)(ws + OFF_CWB) + (long long)l*4096;
        const ushort* cl = (const ushort*)(ws + OFF_CWB) + 16384 + (long long)l*4096;
        B_h[1] = *(const bf16x8*)&ch[o*64 + 8*g];
        B_l[1] = *(const bf16x8*)&cl[o*64 + 8*g];
        B_h[2] = *(const bf16x8*)&ch[o*64 + 32 + 8*g];
        B_l[2] = *(const bf16x8*)&cl[o*64 + 32 + 8*g];
    }
    float cbv = cb[o];
    const ushort* twh = (const ushort*)(ws + OFF_TWA);
    const ushort* twl = twh + 8192;
    const ushort* fh = (const ushort*)(ws + OFF_FWA);
    const ushort* fl = fh + 8192;
    int mtd = wid & 1, ntd = wid >> 1;
    f32x4 accY0 = {0.f,0.f,0.f,0.f}, accY1 = {0.f,0.f,0.f,0.f};
    int keyo = ((o & 7) ^ ((o >> 3) & 7)) << 3;

    for (int half = 0; half < 2; half++) {
        // ---- commit staged registers to LDS ----
        #pragma unroll
        for (int r = 0; r < 4; r++) {
            *(uint4*)&sAhi[sidx[r]] = stH[r];
            *(uint4*)&sAlo[sidx[r]] = stL[r];
        }
        __syncthreads();
        // ---- conv + IDFT-W MFMA ----
        f32x4 acc[8];
        #pragma unroll
        for (int wt = 0; wt < 8; wt++) {
            int gwt = half*8 + wt;
            bf16x8 A0h = *(const bf16x8*)&twh[(gwt*64 + lane)*8];
            bf16x8 A0l = *(const bf16x8*)&twl[(gwt*64 + lane)*8];
            int row = wt*16 + oc;
            int base = row*64;
            int sw = (row & 7) << 3;
            bf16x8 A1h = *(bf16x8*)&sAhi[base + ((8*g) ^ sw)];
            bf16x8 A1l = *(bf16x8*)&sAlo[base + ((8*g) ^ sw)];
            bf16x8 A2h = *(bf16x8*)&sAhi[base + ((32 + 8*g) ^ sw)];
            bf16x8 A2l = *(bf16x8*)&sAlo[base + ((32 + 8*g) ^ sw)];
            f32x4 a = {0.f,0.f,0.f,0.f};
            a = __builtin_amdgcn_mfma_f32_16x16x32_bf16(A0h, B_h[0], a, 0,0,0);
            a = __builtin_amdgcn_mfma_f32_16x16x32_bf16(A0l, B_h[0], a, 0,0,0);
            a = __builtin_amdgcn_mfma_f32_16x16x32_bf16(A0h, B_l[0], a, 0,0,0);
            a = __builtin_amdgcn_mfma_f32_16x16x32_bf16(A1h, B_h[1], a, 0,0,0);
            a = __builtin_amdgcn_mfma_f32_16x16x32_bf16(A1l, B_h[1], a, 0,0,0);
            a = __builtin_amdgcn_mfma_f32_16x16x32_bf16(A1h, B_l[1], a, 0,0,0);
            a = __builtin_amdgcn_mfma_f32_16x16x32_bf16(A2h, B_h[2], a, 0,0,0);
            a = __builtin_amdgcn_mfma_f32_16x16x32_bf16(A2l, B_h[2], a, 0,0,0);
            a = __builtin_amdgcn_mfma_f32_16x16x32_bf16(A2h, B_l[2], a, 0,0,0);
            acc[wt] = a;
        }
        __syncthreads();   // all sA reads done
        // ---- prefetch half-1 h into registers (overlaps epilogue + DFT-W) ----
        if (half == 0) {
            const ushort* srcH = hH + rowbase + 8192;
            const ushort* srcL = hL + rowbase + 8192;
            #pragma unroll
            for (int r = 0; r < 4; r++) {
                int n = r*256 + t;
                int row = n >> 3, i0 = (n & 7)*8;
                stH[r] = *(const uint4*)&srcH[row*64 + i0];
                stL[r] = *(const uint4*)&srcL[row*64 + i0];
            }
        }
        // ---- epilogue: gelu, store h, stage transposed h_new for DFT-W ----
        #pragma unroll
        for (int wt = 0; wt < 8; wt++) {
            U4 hi4, lo4;
            #pragma unroll
            for (int r = 0; r < 4; r++) {
                float v = acc[wt][r] + cbv;
                float gv = GELU(v);
                split2(gv, hi4.u[r], lo4.u[r]);
                long long oaddr = rowbase + (long long)(half*128 + wt*16 + 4*g + r)*64 + o;
                hH[oaddr] = hi4.u[r];
                hL[oaddr] = lo4.u[r];
            }
            if (do_dft) {
                int wl0 = wt*16 + 4*g;
                int tidx = o*128 + (wl0 ^ keyo);
                *(uint2*)&sThi[tidx] = hi4.v;
                *(uint2*)&sTlo[tidx] = lo4.v;
            }
        }
        if (do_dft) {
            __syncthreads();   // sT visible
            #pragma unroll
            for (int ksl = 0; ksl < 4; ksl++) {
                int gks = half*4 + ksl;
                bf16x8 Ah = *(const bf16x8*)&fh[((mtd*8 + gks)*64 + lane)*8];
                bf16x8 Al = *(const bf16x8*)&fl[((mtd*8 + gks)*64 + lane)*8];
                int wof = ksl*32 + 8*g;
                #pragma unroll
                for (int q = 0; q < 2; q++) {
                    int c = (ntd + q*2)*16 + oc;
                    int key = (((c & 7) ^ ((c >> 3) & 7)) << 3);
                    bf16x8 Bh = *(const bf16x8*)&sThi[c*128 + (wof ^ key)];
                    bf16x8 Bl = *(const bf16x8*)&sTlo[c*128 + (wof ^ key)];
                    f32x4 a = q ? accY1 : accY0;
                    a = __builtin_amdgcn_mfma_f32_16x16x32_bf16(Ah, Bh, a, 0,0,0);
                    a = __builtin_amdgcn_mfma_f32_16x16x32_bf16(Al, Bh, a, 0,0,0);
                    a = __builtin_amdgcn_mfma_f32_16x16x32_bf16(Ah, Bl, a, 0,0,0);
                    if (q) accY1 = a; else accY0 = a;
                }
            }
        }
        __syncthreads();   // LDS reads done before next half's commit
    }
    if (do_dft) {
        #pragma unroll
        for (int q = 0; q < 2; q++) {
            f32x4 a = q ? accY1 : accY0;
            int c = (ntd + q*2)*16 + oc;
            #pragma unroll
            for (int r = 0; r < 4; r++) {
                int kk = mtd*16 + 4*g + r;
                int ky = kk >> 1;
                long long addr = ((long long)(b*16 + ky)*256 + hh)*64 + c;
                ws[((kk & 1) ? OFF_Y1IM : OFF_Y1RE) + addr] = a[r];
            }
        }
    }
}

// ---- projection via MFMA, 32-row sub-steps, conflict-free s_u ----
__global__ __launch_bounds__(256) void k_proj(float* ws, const float* p1b,
                                              const float* p2w, const float* p2b, float* out) {
    __shared__ ushort sAhi[64*64];
    __shared__ ushort sAlo[64*64];
    __shared__ float s_u[32*132];
    __shared__ float s_p2[256];
    int t = threadIdx.x;
    int bh = blockIdx.x;
    int lane = t & 63, wid = t >> 6;
    int oc = lane & 15, g = lane >> 4;
    s_p2[t] = p2w[t];
    const ushort* hH = (const ushort*)ws;
    const ushort* hL = (const ushort*)(ws + OFF_HLO_F);
    const ushort* ph = (const ushort*)(ws + OFF_P1T);
    const ushort* pl = ph + 8192;
    bf16x8 Bh[2][2], Bl[2][2];
    float p1bv[2];
    #pragma unroll
    for (int q = 0; q < 2; q++) {
        int u = (wid*2 + q)*16 + oc;
        p1bv[q] = p1b[u];
        #pragma unroll
        for (int ks = 0; ks < 2; ks++) {
            Bh[q][ks] = *(const bf16x8*)&ph[u*64 + ks*32 + 8*g];
            Bl[q][ks] = *(const bf16x8*)&pl[u*64 + ks*32 + 8*g];
        }
    }
    float p2b0 = p2b[0], p2b1 = p2b[1];
    long long rowbase = (long long)bh * 16384;
    float* obase = out + (long long)bh * 512;
    for (int qt = 0; qt < 4; qt++) {
        __syncthreads();
        for (int r = 0; r < 2; r++) {
            int n = r*256 + t;
            int row = n >> 3, i0 = (n & 7)*8;
            long long gidx = rowbase + (long long)(qt*64 + row)*64 + i0;
            int idx = row*64 + (i0 ^ ((row & 7) << 3));
            *(uint4*)&sAhi[idx] = *(const uint4*)&hH[gidx];
            *(uint4*)&sAlo[idx] = *(const uint4*)&hL[gidx];
        }
        __syncthreads();
        for (int sub = 0; sub < 2; sub++) {
            #pragma unroll
            for (int mth = 0; mth < 2; mth++) {
                int mt = sub*2 + mth;
                int row = mt*16 + oc;
                int base = row*64, sw = (row & 7) << 3;
                bf16x8 A0h = *(bf16x8*)&sAhi[base + ((8*g) ^ sw)];
                bf16x8 A0l = *(bf16x8*)&sAlo[base + ((8*g) ^ sw)];
                bf16x8 A1h = *(bf16x8*)&sAhi[base + ((32 + 8*g) ^ sw)];
                bf16x8 A1l = *(bf16x8*)&sAlo[base + ((32 + 8*g) ^ sw)];
                #pragma unroll
                for (int q = 0; q < 2; q++) {
                    f32x4 a = {0.f,0.f,0.f,0.f};
                    a = __builtin_amdgcn_mfma_f32_16x16x32_bf16(A0h, Bh[q][0], a, 0,0,0);
                    a = __builtin_amdgcn_mfma_f32_16x16x32_bf16(A0l, Bh[q][0], a, 0,0,0);
                    a = __builtin_amdgcn_mfma_f32_16x16x32_bf16(A0h, Bl[q][0], a, 0,0,0);
                    a = __builtin_amdgcn_mfma_f32_16x16x32_bf16(A1h, Bh[q][1], a, 0,0,0);
                    a = __builtin_amdgcn_mfma_f32_16x16x32_bf16(A1l, Bh[q][1], a, 0,0,0);
                    a = __builtin_amdgcn_mfma_f32_16x16x32_bf16(A1h, Bl[q][1], a, 0,0,0);
                    int ucol = (wid*2 + q)*16 + oc;
                    int uoff = ucol + (ucol >> 5);
                    #pragma unroll
                    for (int r = 0; r < 4; r++) {
                        float v = a[r] + p1bv[q];
                        s_u[(mth*16 + 4*g + r)*132 + uoff] = GELU(v);
                    }
                }
            }
            __syncthreads();
            {
                int wl = t >> 3, co = (t >> 2) & 1, seg = t & 3;
                float s = 0.f;
                #pragma unroll
                for (int u = 0; u < 32; u++)
                    s += s_u[wl*132 + seg*33 + u] * s_p2[(seg*32 + u)*2 + co];
                s += __shfl_xor(s, 1);
                s += __shfl_xor(s, 2);
                if (seg == 0)
                    obase[(qt*64 + sub*32 + wl)*2 + co] = s + (co ? p2b1 : p2b0);
            }
            __syncthreads();
        }
    }
}

extern "C" void kernel_launch(void* const* d_in, const int* in_sizes, int n_in,
                              void* d_out, int out_size, void* d_ws, size_t ws_size,
                              hipStream_t stream) {
    (void)in_sizes; (void)n_in; (void)out_size; (void)ws_size;
    const float* x   = (const float*)d_in[0];
    const float* lw  = (const float*)d_in[1];
    const float* lb  = (const float*)d_in[2];
    const float* w1r = (const float*)d_in[3];
    const float* w1i = (const float*)d_in[4];
    const float* w2r = (const float*)d_in[5];
    const float* w2i = (const float*)d_in[6];
    const float* cw  = (const float*)d_in[7];
    const float* cb  = (const float*)d_in[8];
    const float* p1w = (const float*)d_in[9];
    const float* p1b = (const float*)d_in[10];
    const float* p2w = (const float*)d_in[11];
    const float* p2b = (const float*)d_in[12];
    float* ws  = (float*)d_ws;
    float* out = (float*)d_out;

    k_init_tables<<<dim3(1), dim3(256), 0, stream>>>(ws);
    k_wtrans<<<dim3(2048), dim3(256), 0, stream>>>(w1r, w1i, w2r, w2i, ws);
    k_cwtrans<<<dim3(64), dim3(256), 0, stream>>>(cw, ws);
    k_p1trans<<<dim3(32), dim3(256), 0, stream>>>(p1w, ws);
    for (int chunk = 0; chunk < 16/CB; chunk++) {
        k_lift<<<dim3(CB*65536/32), dim3(256), 0, stream>>>(x, lw, lb, ws, chunk*CB);
        k_dftw<<<dim3(CB*256), dim3(256), 0, stream>>>(ws);
        for (int l = 0; l < 4; l++) {
            k_dfth<<<dim3(CB*32), dim3(256), 0, stream>>>(ws);
            k_mix<<<dim3(512), dim3(256), 0, stream>>>(ws, l);
            k_layer_out<<<dim3(CB*256), dim3(256), 0, stream>>>(ws, cb + l*64, l, (l < 3) ? 1 : 0);
        }
        k_proj<<<dim3(CB*256), dim3(256), 0, stream>>>(ws, p1b, p2w, p2b,
                                                       out + (long long)chunk*CB*256*256*2);
    }
}

// Round 10
// 1301.996 us; speedup vs baseline: 1.1431x; 1.1431x over previous
//
#include <hip/hip_runtime.h>
#include <math.h>

// FNO2D: B=16, H=W=256, C_IN=C_OUT=2, WIDTH=64, MODES=16, NLAYERS=4
// Partial DFTs (32 kx rows x 16 ky cols). Batch in 2 chunks of CB=8.
// h stored as TWO bf16 planes (hi+lo, exact split of fp32).
// Round-8 structure (best) + coalesced h-store epilogue via sT readback:
// layer_out fuses IDFT-H (front) and DFT-W (back); epilogue stores h
// through the transposed LDS tile with uint4 gathers (no scalar stores).

#define CB 8   // batch chunk size

typedef __attribute__((ext_vector_type(8))) __bf16 bf16x8;
typedef __attribute__((ext_vector_type(4))) float f32x4;

// ---- workspace layout (float offsets), per batch chunk ----
static const long long SZ_HC    = (long long)CB*256*256*64;  // 33,554,432 floats region
static const long long OFF_HLO_F= SZ_HC/2;                   // hi plane: ws[0..), lo plane as ushort
static const long long SZ_Y1C   = (long long)CB*16*256*64;   // 2,097,152 per plane
static const long long OFF_Y1RE = SZ_HC;
static const long long OFF_Y1IM = OFF_Y1RE + SZ_Y1C;
static const long long SZ_FTC   = (long long)CB*32*16*64;    // 262,144 per plane
static const long long OFF_FTRE = OFF_Y1RE + 2*SZ_Y1C;
static const long long OFF_FTIM = OFF_FTRE + SZ_FTC;
static const long long OFF_ORE  = OFF_FTRE + 2*SZ_FTC;
static const long long OFF_OIM  = OFF_FTRE + 3*SZ_FTC;
static const long long SZ_WT    = 4LL*32*16*64*64;           // 8,388,608 per plane
static const long long OFF_WTRE = OFF_FTRE + 4*SZ_FTC;
static const long long OFF_WTIM = OFF_WTRE + SZ_WT;
static const long long OFF_CWT  = OFF_WTIM + SZ_WT;          // legacy slot
static const long long OFF_FW   = OFF_CWT + 4LL*64*64;       // legacy slot
static const long long OFF_TW   = OFF_FW + 256LL*32;         // float2[256] (cos,sin)
static const long long OFF_TWA  = OFF_TW + 512;              // layer_out IDFT-W A frags (hi+lo)
static const long long OFF_CWB  = OFF_TWA + 8192;            // cw bf16 hi+lo
static const long long OFF_FWA  = OFF_CWB + 16384;           // dftw F A-frags hi+lo
static const long long OFF_P1T  = OFF_FWA + 8192;            // p1^T bf16 hi+lo
static const long long WS_FLOATS= OFF_P1T + 8192;            // ~212 MB

#define C2PI 0.0245436926061702596f
#define GELU(v) (0.5f*(v)*(1.0f + erff((v)*0.70710678118654752f)))

__device__ __forceinline__ void split2(float v, ushort& hi, ushort& lo) {
    unsigned u = __float_as_uint(v);
    hi = (ushort)(u >> 16);
    float fhi = __uint_as_float(u & 0xffff0000u);
    float r = v - fhi;
    lo = (ushort)(__float_as_uint(r) >> 16);
}

union U8 { ushort u[8]; uint4 v; };
union U4 { ushort u[4]; uint2 v; };

// ---- tables: TW, layer_out A-frags (TWA), dftw A-frags (FWA) ----
__global__ void k_init_tables(float* ws) {
    int t = threadIdx.x;
    float ang = (float)t * C2PI;
    float s, c;
    sincosf(ang, &s, &c);
    ((float2*)(ws + OFF_TW))[t] = make_float2(c, s);
    // TWA: layer_out A (rows w, K=kk): w = wt*16+(lane&15), kk = 8*(lane>>4)+j
    ushort* twh = (ushort*)(ws + OFF_TWA);
    ushort* twl = twh + 8192;
    int lidx = t & 63;
    int quarter = t >> 6;
    for (int wt = 0; wt < 16; wt++) {
        for (int jq = 0; jq < 2; jq++) {
            int j = quarter*2 + jq;
            int w = wt*16 + (lidx & 15);
            int kk = 8*(lidx >> 4) + j;
            int ky = kk >> 1;
            float a2 = (float)((ky * w) & 255) * C2PI;
            float ss, cc; sincosf(a2, &ss, &cc);
            float val = (kk & 1) ? -ss : cc;
            ushort hi, lo; split2(val, hi, lo);
            twh[(wt*64 + lidx)*8 + j] = hi;
            twl[(wt*64 + lidx)*8 + j] = lo;
        }
    }
    // FWA: dftw A (rows kk, K=w): kk = mt*16+(lane&15), w = ks*32+8*(lane>>4)+j
    ushort* fh = (ushort*)(ws + OFF_FWA);
    ushort* fl = fh + 8192;
    for (int n = t; n < 8192; n += 256) {
        int j = n & 7, ln = (n >> 3) & 63, ks = (n >> 9) & 7, mt2 = n >> 12;
        int kk = mt2*16 + (ln & 15);
        int w = ks*32 + 8*(ln >> 4) + j;
        int ky = kk >> 1;
        float a2 = (float)((ky * w) & 255) * C2PI;
        float ss, cc; sincosf(a2, &ss, &cc);
        float val = (kk & 1) ? -ss : cc;
        ushort hi, lo; split2(val, hi, lo);
        fh[n] = hi; fl[n] = lo;
    }
}

// ---- weight transpose: [l][i][o][x][ky] -> [l][kxi][ky][i][o] ----
__global__ __launch_bounds__(256) void k_wtrans(const float* w1r, const float* w1i,
                                                const float* w2r, const float* w2i,
                                                float* ws) {
    __shared__ float s_t[128*65];
    int t = threadIdx.x;
    int bid = blockIdx.x;                 // 2048 blocks
    int p    = bid & 1;
    int mh   = (bid >> 1) & 1;
    int tsel = (bid >> 2) & 1;
    int i    = (bid >> 3) & 63;
    int l    = bid >> 9;
    const float* src = tsel == 0 ? (p ? w1i : w1r) : (p ? w2i : w2r);
    const float* srcbase = src + ((long long)(l*64 + i)*64)*256;
    int msub = mh*128;
    for (int j = 0; j < 8; j++) {
        int n = j*256 + t;
        int o = n >> 5, mf4 = n & 31;
        float4 v = *(const float4*)(srcbase + o*256 + msub + mf4*4);
        int m0 = mf4*4;
        s_t[(m0+0)*65 + o] = v.x;
        s_t[(m0+1)*65 + o] = v.y;
        s_t[(m0+2)*65 + o] = v.z;
        s_t[(m0+3)*65 + o] = v.w;
    }
    __syncthreads();
    float* dst = ws + (p ? OFF_WTIM : OFF_WTRE);
    int o4 = t & 15, mq = t >> 4;
    for (int it = 0; it < 8; it++) {
        int ml = it*16 + mq;
        float4 w = make_float4(s_t[ml*65 + o4*4 + 0], s_t[ml*65 + o4*4 + 1],
                               s_t[ml*65 + o4*4 + 2], s_t[ml*65 + o4*4 + 3]);
        long long idx = ((long long)(l*512 + tsel*256 + msub + ml))*4096 + i*64 + o4*4;
        *(float4*)(dst + idx) = w;
    }
}

// ---- cw -> bf16 hi/lo planes [l][o][i] ----
__global__ void k_cwtrans(const float* cw, float* ws) {
    int gid = blockIdx.x * 256 + threadIdx.x;  // 16384
    ushort* ch = (ushort*)(ws + OFF_CWB);
    ushort* cl = ch + 16384;
    ushort hi, lo; split2(cw[gid], hi, lo);
    ch[gid] = hi; cl[gid] = lo;
}

// ---- p1 transpose -> bf16 hi/lo planes p1t[u(128)][i(64)] ----
__global__ void k_p1trans(const float* p1w, float* ws) {
    int gid = blockIdx.x * 256 + threadIdx.x;  // 8192
    int u = gid >> 6, i = gid & 63;
    ushort* ph = (ushort*)(ws + OFF_P1T);
    ushort hi, lo; split2(p1w[i*128 + u], hi, lo);
    ph[gid] = hi; ph[8192 + gid] = lo;
}

// ---- lift: h = x@lw + lb, split to hi/lo planes ----
__global__ __launch_bounds__(256) void k_lift(const float* x, const float* lw,
                                              const float* lb, float* ws, int bbase) {
    long long gid8 = (long long)blockIdx.x * 256 + threadIdx.x;  // < CB*65536*8
    int c0 = (int)(gid8 & 7) * 8;
    long long pixl = gid8 >> 3;
    const float* xp = x + ((long long)bbase*65536 + pixl)*2;
    float x0 = xp[0], x1 = xp[1];
    U8 hi, lo;
    #pragma unroll
    for (int j = 0; j < 8; j++) {
        int c = c0 + j;
        float v = x0*lw[c] + x1*lw[64 + c] + lb[c];
        split2(v, hi.u[j], lo.u[j]);
    }
    ushort* hH = (ushort*)ws;
    ushort* hL = (ushort*)(ws + OFF_HLO_F);
    *(uint4*)&hH[pixl*64 + c0] = hi.v;
    *(uint4*)&hL[pixl*64 + c0] = lo.v;
}

// ---- chunk-initial DFT-W via MFMA: Y1[kk(32) x c(64)] = F[32x256]@h[256x64] ----
__global__ __launch_bounds__(256) void k_dftw(float* ws) {
    __shared__ ushort sBhi[64*128];
    __shared__ ushort sBlo[64*128];
    int t = threadIdx.x;
    int bh = blockIdx.x;                  // CB*256
    int lane = t & 63, wid = t >> 6;
    int oc = lane & 15, g = lane >> 4;
    const ushort* hH = (const ushort*)ws;
    const ushort* hL = (const ushort*)(ws + OFF_HLO_F);
    const ushort* fh = (const ushort*)(ws + OFF_FWA);
    const ushort* fl = fh + 8192;
    int mt = wid & 1, nt0 = wid >> 1;
    f32x4 acc0 = {0.f,0.f,0.f,0.f}, acc1 = {0.f,0.f,0.f,0.f};
    long long rowbase = (long long)bh * 16384;
    for (int half = 0; half < 2; half++) {
        __syncthreads();
        for (int r = 0; r < 2; r++) {
            int n = r*256 + t;            // 0..511
            int c0 = (n & 7) * 8;
            int w = (n >> 3) * 2;         // 0..126
            long long gidx = rowbase + (long long)(half*128 + w)*64 + c0;
            U8 a, b2;
            a.v  = *(const uint4*)&hH[gidx];
            b2.v = *(const uint4*)&hH[gidx + 64];
            #pragma unroll
            for (int j = 0; j < 8; j++) {
                int c = c0 + j;
                int key = (((c & 7) ^ ((c >> 3) & 7)) << 3);
                *(uint*)&sBhi[c*128 + (w ^ key)] = (uint)a.u[j] | ((uint)b2.u[j] << 16);
            }
            a.v  = *(const uint4*)&hL[gidx];
            b2.v = *(const uint4*)&hL[gidx + 64];
            #pragma unroll
            for (int j = 0; j < 8; j++) {
                int c = c0 + j;
                int key = (((c & 7) ^ ((c >> 3) & 7)) << 3);
                *(uint*)&sBlo[c*128 + (w ^ key)] = (uint)a.u[j] | ((uint)b2.u[j] << 16);
            }
        }
        __syncthreads();
        #pragma unroll
        for (int ksl = 0; ksl < 4; ksl++) {
            int gks = half*4 + ksl;
            bf16x8 Ah = *(const bf16x8*)&fh[((mt*8 + gks)*64 + lane)*8];
            bf16x8 Al = *(const bf16x8*)&fl[((mt*8 + gks)*64 + lane)*8];
            int wof = ksl*32 + 8*g;
            #pragma unroll
            for (int q = 0; q < 2; q++) {
                int c = (nt0 + q*2)*16 + oc;
                int key = (((c & 7) ^ ((c >> 3) & 7)) << 3);
                bf16x8 Bh = *(const bf16x8*)&sBhi[c*128 + (wof ^ key)];
                bf16x8 Bl = *(const bf16x8*)&sBlo[c*128 + (wof ^ key)];
                f32x4 a = q ? acc1 : acc0;
                a = __builtin_amdgcn_mfma_f32_16x16x32_bf16(Ah, Bh, a, 0,0,0);
                a = __builtin_amdgcn_mfma_f32_16x16x32_bf16(Al, Bh, a, 0,0,0);
                a = __builtin_amdgcn_mfma_f32_16x16x32_bf16(Ah, Bl, a, 0,0,0);
                if (q) acc1 = a; else acc0 = a;
            }
        }
    }
    int b = bh >> 8, hh = bh & 255;
    #pragma unroll
    for (int q = 0; q < 2; q++) {
        f32x4 a = q ? acc1 : acc0;
        int c = (nt0 + q*2)*16 + oc;
        #pragma unroll
        for (int r = 0; r < 4; r++) {
            int kk = mt*16 + 4*g + r;
            int ky = kk >> 1;
            long long addr = ((long long)(b*16 + ky)*256 + hh)*64 + c;
            ws[((kk & 1) ? OFF_Y1IM : OFF_Y1RE) + addr] = a[r];
        }
    }
}

// ---- DFT along H (fp32 VALU) ----
__global__ __launch_bounds__(256) void k_dfth(float* ws) {
    __shared__ __align__(16) float s_yre[64*32];
    __shared__ __align__(16) float s_yim[64*32];
    __shared__ __align__(16) float s_tw[512];
    int t = threadIdx.x;
    int bk = blockIdx.x;
    int chalf = bk & 1;
    int ky = (bk >> 1) & 15;
    int b = bk >> 5;
    ((float2*)s_tw)[t] = ((const float2*)(ws + OFF_TW))[t];
    int kxi = t & 31;
    int cq = t >> 5;
    int kxa = (kxi < 16) ? kxi : (224 + kxi);
    float accRe[4] = {0.f,0.f,0.f,0.f}, accIm[4] = {0.f,0.f,0.f,0.f};
    const float* yre = ws + OFF_Y1RE + (long long)(b*16 + ky)*(256*64);
    const float* yim = ws + OFF_Y1IM + (long long)(b*16 + ky)*(256*64);
    for (int chunk = 0; chunk < 4; chunk++) {
        __syncthreads();
        for (int j = 0; j < 2; j++) {
            int n = j*256 + t;
            int hl = n >> 3, c4 = n & 7;
            long long soff = (long long)(chunk*64 + hl)*64 + chalf*32 + c4*4;
            ((float4*)s_yre)[hl*8 + c4] = *(const float4*)(yre + soff);
            ((float4*)s_yim)[hl*8 + c4] = *(const float4*)(yim + soff);
        }
        __syncthreads();
        for (int hl = 0; hl < 64; hl++) {
            int h = chunk*64 + hl;
            float2 tw = ((const float2*)s_tw)[(kxa*h) & 255];
            float4 yr = *(const float4*)&s_yre[hl*32 + 4*cq];
            float4 yi = *(const float4*)&s_yim[hl*32 + 4*cq];
            accRe[0] += yr.x*tw.x + yi.x*tw.y;
            accRe[1] += yr.y*tw.x + yi.y*tw.y;
            accRe[2] += yr.z*tw.x + yi.z*tw.y;
            accRe[3] += yr.w*tw.x + yi.w*tw.y;
            accIm[0] += yi.x*tw.x - yr.x*tw.y;
            accIm[1] += yi.y*tw.x - yr.y*tw.y;
            accIm[2] += yi.z*tw.x - yr.z*tw.y;
            accIm[3] += yi.w*tw.x - yr.w*tw.y;
        }
    }
    long long base = ((long long)((b*32 + kxi)*16 + ky))*64 + chalf*32 + 4*cq;
    *(float4*)&ws[OFF_FTRE + base] = make_float4(accRe[0], accRe[1], accRe[2], accRe[3]);
    *(float4*)&ws[OFF_FTIM + base] = make_float4(accIm[0], accIm[1], accIm[2], accIm[3]);
}

// ---- mode mix ----
__global__ __launch_bounds__(256) void k_mix(float* ws, int l) {
    __shared__ __align__(16) float2 s_ft[CB*64];
    int t = threadIdx.x;
    int kk = blockIdx.x;
    int kxi = kk >> 4, ky = kk & 15;
    for (int j = 0; j < 2; j++) {
        int idx = j*256 + t;
        int i = idx & 63, b = idx >> 6;
        long long a = ((long long)(b*32 + kxi)*16 + ky)*64 + i;
        s_ft[b*64 + i] = make_float2(ws[OFF_FTRE + a], ws[OFF_FTIM + a]);
    }
    __syncthreads();
    int o = t & 63, bq = t >> 6;
    const float* wr = ws + OFF_WTRE + (((long long)l*32 + kxi)*16 + ky)*4096;
    const float* wi = ws + OFF_WTIM + (((long long)l*32 + kxi)*16 + ky)*4096;
    float accRe[2] = {0.f,0.f}, accIm[2] = {0.f,0.f};
    #pragma unroll 4
    for (int i = 0; i < 64; i++) {
        float wrv = wr[i*64 + o], wiv = wi[i*64 + o];
        #pragma unroll
        for (int j = 0; j < 2; j++) {
            float2 a = s_ft[(bq*2 + j)*64 + i];
            accRe[j] += a.x*wrv - a.y*wiv;
            accIm[j] += a.x*wiv + a.y*wrv;
        }
    }
    #pragma unroll
    for (int j = 0; j < 2; j++) {
        int b = bq*2 + j;
        long long a = ((long long)(b*32 + kxi)*16 + ky)*64 + o;
        ws[OFF_ORE + a] = accRe[j];
        ws[OFF_OIM + a] = accIm[j];
    }
}

// ---- fused layer: IDFT-H(O)->B; conv+IDFT-W MFMA; gelu->sT; DFT-W->Y1;
//      h stored via coalesced uint4 gathers from sT ----
__global__ __launch_bounds__(256) void k_layer_out(float* ws, const float* cb, int l, int do_dft) {
    __shared__ __align__(16) ushort sMem[16384];   // 32 KB union
    ushort* sBhi = sMem;          // conv-B 64*104
    ushort* sBlo = sMem + 6656;
    ushort* sAhi = sMem;          // h_old staging 128*64 (swizzled)
    ushort* sAlo = sMem + 8192;
    ushort* sThi = sMem;          // h_new transposed 64*128 (swizzled)
    ushort* sTlo = sMem + 8192;
    int t = threadIdx.x;
    int bh = blockIdx.x;
    int lane = t & 63, wid = t >> 6;
    int oc = lane & 15, g = lane >> 4;
    int b = bh >> 8, hh = bh & 255;
    ushort* hH = (ushort*)ws;
    ushort* hL = (ushort*)(ws + OFF_HLO_F);

    // ---- B: g part via fused IDFT-H from O (k=0..31) ----
    {
        int ky = t >> 4, o0 = (t & 15) * 4;
        const float* ore = ws + OFF_ORE;
        const float* oim = ws + OFF_OIM;
        const float2* twg = (const float2*)(ws + OFF_TW);
        float gr0=0,gr1=0,gr2=0,gr3=0, gi0=0,gi1=0,gi2=0,gi3=0;
        #pragma unroll 8
        for (int kxi = 0; kxi < 32; kxi++) {
            int kxa = (kxi < 16) ? kxi : (224 + kxi);
            float2 tw = twg[(kxa * hh) & 255];
            long long a = ((long long)((b*32 + kxi)*16 + ky))*64 + o0;
            float4 vr = *(const float4*)(ore + a);
            float4 vi = *(const float4*)(oim + a);
            gr0 += vr.x*tw.x - vi.x*tw.y;  gi0 += vr.x*tw.y + vi.x*tw.x;
            gr1 += vr.y*tw.x - vi.y*tw.y;  gi1 += vr.y*tw.y + vi.y*tw.x;
            gr2 += vr.z*tw.x - vi.z*tw.y;  gi2 += vr.z*tw.y + vi.z*tw.x;
            gr3 += vr.w*tw.x - vi.w*tw.y;  gi3 += vr.w*tw.y + vi.w*tw.x;
        }
        float scale = (ky == 0 ? 1.0f : 2.0f) * (1.0f/65536.0f);
        float grs[4] = {gr0,gr1,gr2,gr3}, gis[4] = {gi0,gi1,gi2,gi3};
        #pragma unroll
        for (int j = 0; j < 4; j++) {
            ushort h0,l0,h1,l1;
            split2(grs[j]*scale, h0, l0);
            split2(gis[j]*scale, h1, l1);
            int idx = (o0 + j)*104 + 2*ky;
            sBhi[idx] = h0; sBhi[idx+1] = h1;
            sBlo[idx] = l0; sBlo[idx+1] = l1;
        }
    }
    // ---- B: cw part (k=32..95) ----
    {
        const ushort* ch = (const ushort*)(ws + OFF_CWB) + (long long)l*4096;
        const ushort* clo = (const ushort*)(ws + OFF_CWB) + 16384 + (long long)l*4096;
        for (int n = t; n < 512; n += 256) {
            int o = n >> 3, i0 = (n & 7)*8;
            *(uint4*)&sBhi[o*104 + 32 + i0] = *(const uint4*)&ch[o*64 + i0];
            *(uint4*)&sBlo[o*104 + 32 + i0] = *(const uint4*)&clo[o*64 + i0];
        }
    }
    __syncthreads();
    int o = wid*16 + oc;
    bf16x8 B_h[3], B_l[3];
    #pragma unroll
    for (int s = 0; s < 3; s++) {
        int kb = 32*s + 8*g;
        B_h[s] = *(bf16x8*)&sBhi[o*104 + kb];
        B_l[s] = *(bf16x8*)&sBlo[o*104 + kb];
    }
    __syncthreads();   // B-frag reads done before sA overwrites the region
    float cbv = cb[o];
    const ushort* twh = (const ushort*)(ws + OFF_TWA);
    const ushort* twl = twh + 8192;
    const ushort* fh = (const ushort*)(ws + OFF_FWA);
    const ushort* fl = fh + 8192;
    long long rowbase = (long long)bh * 16384;
    int mtd = wid & 1, ntd = wid >> 1;
    f32x4 accY0 = {0.f,0.f,0.f,0.f}, accY1 = {0.f,0.f,0.f,0.f};
    int keyo = ((o & 7) ^ ((o >> 3) & 7)) << 3;

    for (int half = 0; half < 2; half++) {
        // ---- stage h_old ----
        const ushort* srcH = hH + rowbase + half*8192;
        const ushort* srcL = hL + rowbase + half*8192;
        for (int n = t; n < 1024; n += 256) {
            int row = n >> 3, i0 = (n & 7)*8;
            int idx = row*64 + (i0 ^ ((row & 7) << 3));
            *(uint4*)&sAhi[idx] = *(const uint4*)&srcH[row*64 + i0];
            *(uint4*)&sAlo[idx] = *(const uint4*)&srcL[row*64 + i0];
        }
        __syncthreads();
        // ---- conv + IDFT-W MFMA ----
        f32x4 acc[8];
        #pragma unroll
        for (int wt = 0; wt < 8; wt++) {
            int gwt = half*8 + wt;
            bf16x8 A0h = *(const bf16x8*)&twh[(gwt*64 + lane)*8];
            bf16x8 A0l = *(const bf16x8*)&twl[(gwt*64 + lane)*8];
            int row = wt*16 + oc;
            int base = row*64;
            int sw = (row & 7) << 3;
            bf16x8 A1h = *(bf16x8*)&sAhi[base + ((8*g) ^ sw)];
            bf16x8 A1l = *(bf16x8*)&sAlo[base + ((8*g) ^ sw)];
            bf16x8 A2h = *(bf16x8*)&sAhi[base + ((32 + 8*g) ^ sw)];
            bf16x8 A2l = *(bf16x8*)&sAlo[base + ((32 + 8*g) ^ sw)];
            f32x4 a = {0.f,0.f,0.f,0.f};
            a = __builtin_amdgcn_mfma_f32_16x16x32_bf16(A0h, B_h[0], a, 0,0,0);
            a = __builtin_amdgcn_mfma_f32_16x16x32_bf16(A0l, B_h[0], a, 0,0,0);
            a = __builtin_amdgcn_mfma_f32_16x16x32_bf16(A0h, B_l[0], a, 0,0,0);
            a = __builtin_amdgcn_mfma_f32_16x16x32_bf16(A1h, B_h[1], a, 0,0,0);
            a = __builtin_amdgcn_mfma_f32_16x16x32_bf16(A1l, B_h[1], a, 0,0,0);
            a = __builtin_amdgcn_mfma_f32_16x16x32_bf16(A1h, B_l[1], a, 0,0,0);
            a = __builtin_amdgcn_mfma_f32_16x16x32_bf16(A2h, B_h[2], a, 0,0,0);
            a = __builtin_amdgcn_mfma_f32_16x16x32_bf16(A2l, B_h[2], a, 0,0,0);
            a = __builtin_amdgcn_mfma_f32_16x16x32_bf16(A2h, B_l[2], a, 0,0,0);
            acc[wt] = a;
        }
        __syncthreads();   // sA reads done; sT may overwrite
        // ---- epilogue: gelu + split -> transposed LDS tile only ----
        #pragma unroll
        for (int wt = 0; wt < 8; wt++) {
            U4 hi4, lo4;
            #pragma unroll
            for (int r = 0; r < 4; r++) {
                float v = acc[wt][r] + cbv;
                float gv = GELU(v);
                split2(gv, hi4.u[r], lo4.u[r]);
            }
            int wl0 = wt*16 + 4*g;
            int tidx = o*128 + (wl0 ^ keyo);
            *(uint2*)&sThi[tidx] = hi4.v;
            *(uint2*)&sTlo[tidx] = lo4.v;
        }
        __syncthreads();   // sT visible to all
        // ---- DFT-W from sT (accumulate Y1) ----
        if (do_dft) {
            #pragma unroll
            for (int ksl = 0; ksl < 4; ksl++) {
                int gks = half*4 + ksl;
                bf16x8 Ah = *(const bf16x8*)&fh[((mtd*8 + gks)*64 + lane)*8];
                bf16x8 Al = *(const bf16x8*)&fl[((mtd*8 + gks)*64 + lane)*8];
                int wof = ksl*32 + 8*g;
                #pragma unroll
                for (int q = 0; q < 2; q++) {
                    int c = (ntd + q*2)*16 + oc;
                    int key = (((c & 7) ^ ((c >> 3) & 7)) << 3);
                    bf16x8 Bh = *(const bf16x8*)&sThi[c*128 + (wof ^ key)];
                    bf16x8 Bl = *(const bf16x8*)&sTlo[c*128 + (wof ^ key)];
                    f32x4 a = q ? accY1 : accY0;
                    a = __builtin_amdgcn_mfma_f32_16x16x32_bf16(Ah, Bh, a, 0,0,0);
                    a = __builtin_amdgcn_mfma_f32_16x16x32_bf16(Al, Bh, a, 0,0,0);
                    a = __builtin_amdgcn_mfma_f32_16x16x32_bf16(Ah, Bl, a, 0,0,0);
                    if (q) accY1 = a; else accY0 = a;
                }
            }
        }
        // ---- gather from sT -> coalesced uint4 h stores ----
        {
            ushort* dstH = hH + rowbase + half*8192;
            ushort* dstL = hL + rowbase + half*8192;
            #pragma unroll
            for (int r = 0; r < 4; r++) {
                int n = r*256 + t;
                int w = n >> 3, o0 = (n & 7)*8;
                U8 oh, ol;
                #pragma unroll
                for (int j = 0; j < 8; j++) {
                    int oo = o0 + j;
                    int key = (((oo & 7) ^ ((oo >> 3) & 7)) << 3);
                    oh.u[j] = sThi[oo*128 + (w ^ key)];
                    ol.u[j] = sTlo[oo*128 + (w ^ key)];
                }
                *(uint4*)&dstH[w*64 + o0] = oh.v;
                *(uint4*)&dstL[w*64 + o0] = ol.v;
            }
        }
        __syncthreads();   // sT reads done before next half's sA commit
    }
    if (do_dft) {
        #pragma unroll
        for (int q = 0; q < 2; q++) {
            f32x4 a = q ? accY1 : accY0;
            int c = (ntd + q*2)*16 + oc;
            #pragma unroll
            for (int r = 0; r < 4; r++) {
                int kk = mtd*16 + 4*g + r;
                int ky = kk >> 1;
                long long addr = ((long long)(b*16 + ky)*256 + hh)*64 + c;
                ws[((kk & 1) ? OFF_Y1IM : OFF_Y1RE) + addr] = a[r];
            }
        }
    }
}

// ---- projection via MFMA, 32-row sub-steps, conflict-free s_u ----
__global__ __launch_bounds__(256) void k_proj(float* ws, const float* p1b,
                                              const float* p2w, const float* p2b, float* out) {
    __shared__ ushort sAhi[64*64];
    __shared__ ushort sAlo[64*64];
    __shared__ float s_u[32*132];
    __shared__ float s_p2[256];
    int t = threadIdx.x;
    int bh = blockIdx.x;
    int lane = t & 63, wid = t >> 6;
    int oc = lane & 15, g = lane >> 4;
    s_p2[t] = p2w[t];
    const ushort* hH = (const ushort*)ws;
    const ushort* hL = (const ushort*)(ws + OFF_HLO_F);
    const ushort* ph = (const ushort*)(ws + OFF_P1T);
    const ushort* pl = ph + 8192;
    bf16x8 Bh[2][2], Bl[2][2];
    float p1bv[2];
    #pragma unroll
    for (int q = 0; q < 2; q++) {
        int u = (wid*2 + q)*16 + oc;
        p1bv[q] = p1b[u];
        #pragma unroll
        for (int ks = 0; ks < 2; ks++) {
            Bh[q][ks] = *(const bf16x8*)&ph[u*64 + ks*32 + 8*g];
            Bl[q][ks] = *(const bf16x8*)&pl[u*64 + ks*32 + 8*g];
        }
    }
    float p2b0 = p2b[0], p2b1 = p2b[1];
    long long rowbase = (long long)bh * 16384;
    float* obase = out + (long long)bh * 512;
    for (int qt = 0; qt < 4; qt++) {
        __syncthreads();
        for (int r = 0; r < 2; r++) {
            int n = r*256 + t;
            int row = n >> 3, i0 = (n & 7)*8;
            long long gidx = rowbase + (long long)(qt*64 + row)*64 + i0;
            int idx = row*64 + (i0 ^ ((row & 7) << 3));
            *(uint4*)&sAhi[idx] = *(const uint4*)&hH[gidx];
            *(uint4*)&sAlo[idx] = *(const uint4*)&hL[gidx];
        }
        __syncthreads();
        for (int sub = 0; sub < 2; sub++) {
            #pragma unroll
            for (int mth = 0; mth < 2; mth++) {
                int mt = sub*2 + mth;
                int row = mt*16 + oc;
                int base = row*64, sw = (row & 7) << 3;
                bf16x8 A0h = *(bf16x8*)&sAhi[base + ((8*g) ^ sw)];
                bf16x8 A0l = *(bf16x8*)&sAlo[base + ((8*g) ^ sw)];
                bf16x8 A1h = *(bf16x8*)&sAhi[base + ((32 + 8*g) ^ sw)];
                bf16x8 A1l = *(bf16x8*)&sAlo[base + ((32 + 8*g) ^ sw)];
                #pragma unroll
                for (int q = 0; q < 2; q++) {
                    f32x4 a = {0.f,0.f,0.f,0.f};
                    a = __builtin_amdgcn_mfma_f32_16x16x32_bf16(A0h, Bh[q][0], a, 0,0,0);
                    a = __builtin_amdgcn_mfma_f32_16x16x32_bf16(A0l, Bh[q][0], a, 0,0,0);
                    a = __builtin_amdgcn_mfma_f32_16x16x32_bf16(A0h, Bl[q][0], a, 0,0,0);
                    a = __builtin_amdgcn_mfma_f32_16x16x32_bf16(A1h, Bh[q][1], a, 0,0,0);
                    a = __builtin_amdgcn_mfma_f32_16x16x32_bf16(A1l, Bh[q][1], a, 0,0,0);
                    a = __builtin_amdgcn_mfma_f32_16x16x32_bf16(A1h, Bl[q][1], a, 0,0,0);
                    int ucol = (wid*2 + q)*16 + oc;
                    int uoff = ucol + (ucol >> 5);
                    #pragma unroll
                    for (int r = 0; r < 4; r++) {
                        float v = a[r] + p1bv[q];
                        s_u[(mth*16 + 4*g + r)*132 + uoff] = GELU(v);
                    }
                }
            }
            __syncthreads();
            {
                int wl = t >> 3, co = (t >> 2) & 1, seg = t & 3;
                float s = 0.f;
                #pragma unroll
                for (int u = 0; u < 32; u++)
                    s += s_u[wl*132 + seg*33 + u] * s_p2[(seg*32 + u)*2 + co];
                s += __shfl_xor(s, 1);
                s += __shfl_xor(s, 2);
                if (seg == 0)
                    obase[(qt*64 + sub*32 + wl)*2 + co] = s + (co ? p2b1 : p2b0);
            }
            __syncthreads();
        }
    }
}

extern "C" void kernel_launch(void* const* d_in, const int* in_sizes, int n_in,
                              void* d_out, int out_size, void* d_ws, size_t ws_size,
                              hipStream_t stream) {
    (void)in_sizes; (void)n_in; (void)out_size; (void)ws_size;
    const float* x   = (const float*)d_in[0];
    const float* lw  = (const float*)d_in[1];
    const float* lb  = (const float*)d_in[2];
    const float* w1r = (const float*)d_in[3];
    const float* w1i = (const float*)d_in[4];
    const float* w2r = (const float*)d_in[5];
    const float* w2i = (const float*)d_in[6];
    const float* cw  = (const float*)d_in[7];
    const float* cb  = (const float*)d_in[8];
    const float* p1w = (const float*)d_in[9];
    const float* p1b = (const float*)d_in[10];
    const float* p2w = (const float*)d_in[11];
    const float* p2b = (const float*)d_in[12];
    float* ws  = (float*)d_ws;
    float* out = (float*)d_out;

    k_init_tables<<<dim3(1), dim3(256), 0, stream>>>(ws);
    k_wtrans<<<dim3(2048), dim3(256), 0, stream>>>(w1r, w1i, w2r, w2i, ws);
    k_cwtrans<<<dim3(64), dim3(256), 0, stream>>>(cw, ws);
    k_p1trans<<<dim3(32), dim3(256), 0, stream>>>(p1w, ws);
    for (int chunk = 0; chunk < 16/CB; chunk++) {
        k_lift<<<dim3(CB*65536/32), dim3(256), 0, stream>>>(x, lw, lb, ws, chunk*CB);
        k_dftw<<<dim3(CB*256), dim3(256), 0, stream>>>(ws);
        for (int l = 0; l < 4; l++) {
            k_dfth<<<dim3(CB*32), dim3(256), 0, stream>>>(ws);
            k_mix<<<dim3(512), dim3(256), 0, stream>>>(ws, l);
            k_layer_out<<<dim3(CB*256), dim3(256), 0, stream>>>(ws, cb + l*64, l, (l < 3) ? 1 : 0);
        }
        k_proj<<<dim3(CB*256), dim3(256), 0, stream>>>(ws, p1b, p2w, p2b,
                                                       out + (long long)chunk*CB*256*256*2);
    }
}

// Round 11
// 1166.661 us; speedup vs baseline: 1.2757x; 1.1160x over previous
//
#include <hip/hip_runtime.h>
#include <math.h>

// FNO2D: B=16, H=W=256, C_IN=C_OUT=2, WIDTH=64, MODES=16, NLAYERS=4
// Partial DFTs (32 kx rows x 16 ky cols). Batch in 2 chunks of CB=8.
// h stored as TWO bf16 planes (hi+lo, exact split of fp32).
// Round-8 structure + (a) 512-thread layer_out (halved per-wave phase
// work, 8 waves/block), (b) lift fused into chunk-initial DFT-W.

#define CB 8   // batch chunk size

typedef __attribute__((ext_vector_type(8))) __bf16 bf16x8;
typedef __attribute__((ext_vector_type(4))) float f32x4;

// ---- workspace layout (float offsets), per batch chunk ----
static const long long SZ_HC    = (long long)CB*256*256*64;  // 33,554,432 floats region
static const long long OFF_HLO_F= SZ_HC/2;                   // hi plane: ws[0..), lo plane as ushort
static const long long SZ_Y1C   = (long long)CB*16*256*64;   // 2,097,152 per plane
static const long long OFF_Y1RE = SZ_HC;
static const long long OFF_Y1IM = OFF_Y1RE + SZ_Y1C;
static const long long SZ_FTC   = (long long)CB*32*16*64;    // 262,144 per plane
static const long long OFF_FTRE = OFF_Y1RE + 2*SZ_Y1C;
static const long long OFF_FTIM = OFF_FTRE + SZ_FTC;
static const long long OFF_ORE  = OFF_FTRE + 2*SZ_FTC;
static const long long OFF_OIM  = OFF_FTRE + 3*SZ_FTC;
static const long long SZ_WT    = 4LL*32*16*64*64;           // 8,388,608 per plane
static const long long OFF_WTRE = OFF_FTRE + 4*SZ_FTC;
static const long long OFF_WTIM = OFF_WTRE + SZ_WT;
static const long long OFF_CWT  = OFF_WTIM + SZ_WT;          // legacy slot
static const long long OFF_FW   = OFF_CWT + 4LL*64*64;       // legacy slot
static const long long OFF_TW   = OFF_FW + 256LL*32;         // float2[256] (cos,sin)
static const long long OFF_TWA  = OFF_TW + 512;              // layer_out IDFT-W A frags (hi+lo)
static const long long OFF_CWB  = OFF_TWA + 8192;            // cw bf16 hi+lo
static const long long OFF_FWA  = OFF_CWB + 16384;           // dftw F A-frags hi+lo
static const long long OFF_P1T  = OFF_FWA + 8192;            // p1^T bf16 hi+lo
static const long long WS_FLOATS= OFF_P1T + 8192;            // ~212 MB

#define C2PI 0.0245436926061702596f
#define GELU(v) (0.5f*(v)*(1.0f + erff((v)*0.70710678118654752f)))

__device__ __forceinline__ void split2(float v, ushort& hi, ushort& lo) {
    unsigned u = __float_as_uint(v);
    hi = (ushort)(u >> 16);
    float fhi = __uint_as_float(u & 0xffff0000u);
    float r = v - fhi;
    lo = (ushort)(__float_as_uint(r) >> 16);
}

union U8 { ushort u[8]; uint4 v; };
union U4 { ushort u[4]; uint2 v; };

// ---- tables: TW, layer_out A-frags (TWA), dftw A-frags (FWA) ----
__global__ void k_init_tables(float* ws) {
    int t = threadIdx.x;
    float ang = (float)t * C2PI;
    float s, c;
    sincosf(ang, &s, &c);
    ((float2*)(ws + OFF_TW))[t] = make_float2(c, s);
    // TWA: layer_out A (rows w, K=kk): w = wt*16+(lane&15), kk = 8*(lane>>4)+j
    ushort* twh = (ushort*)(ws + OFF_TWA);
    ushort* twl = twh + 8192;
    int lidx = t & 63;
    int quarter = t >> 6;
    for (int wt = 0; wt < 16; wt++) {
        for (int jq = 0; jq < 2; jq++) {
            int j = quarter*2 + jq;
            int w = wt*16 + (lidx & 15);
            int kk = 8*(lidx >> 4) + j;
            int ky = kk >> 1;
            float a2 = (float)((ky * w) & 255) * C2PI;
            float ss, cc; sincosf(a2, &ss, &cc);
            float val = (kk & 1) ? -ss : cc;
            ushort hi, lo; split2(val, hi, lo);
            twh[(wt*64 + lidx)*8 + j] = hi;
            twl[(wt*64 + lidx)*8 + j] = lo;
        }
    }
    // FWA: dftw A (rows kk, K=w): kk = mt*16+(lane&15), w = ks*32+8*(lane>>4)+j
    ushort* fh = (ushort*)(ws + OFF_FWA);
    ushort* fl = fh + 8192;
    for (int n = t; n < 8192; n += 256) {
        int j = n & 7, ln = (n >> 3) & 63, ks = (n >> 9) & 7, mt2 = n >> 12;
        int kk = mt2*16 + (ln & 15);
        int w = ks*32 + 8*(ln >> 4) + j;
        int ky = kk >> 1;
        float a2 = (float)((ky * w) & 255) * C2PI;
        float ss, cc; sincosf(a2, &ss, &cc);
        float val = (kk & 1) ? -ss : cc;
        ushort hi, lo; split2(val, hi, lo);
        fh[n] = hi; fl[n] = lo;
    }
}

// ---- weight transpose: [l][i][o][x][ky] -> [l][kxi][ky][i][o] ----
__global__ __launch_bounds__(256) void k_wtrans(const float* w1r, const float* w1i,
                                                const float* w2r, const float* w2i,
                                                float* ws) {
    __shared__ float s_t[128*65];
    int t = threadIdx.x;
    int bid = blockIdx.x;                 // 2048 blocks
    int p    = bid & 1;
    int mh   = (bid >> 1) & 1;
    int tsel = (bid >> 2) & 1;
    int i    = (bid >> 3) & 63;
    int l    = bid >> 9;
    const float* src = tsel == 0 ? (p ? w1i : w1r) : (p ? w2i : w2r);
    const float* srcbase = src + ((long long)(l*64 + i)*64)*256;
    int msub = mh*128;
    for (int j = 0; j < 8; j++) {
        int n = j*256 + t;
        int o = n >> 5, mf4 = n & 31;
        float4 v = *(const float4*)(srcbase + o*256 + msub + mf4*4);
        int m0 = mf4*4;
        s_t[(m0+0)*65 + o] = v.x;
        s_t[(m0+1)*65 + o] = v.y;
        s_t[(m0+2)*65 + o] = v.z;
        s_t[(m0+3)*65 + o] = v.w;
    }
    __syncthreads();
    float* dst = ws + (p ? OFF_WTIM : OFF_WTRE);
    int o4 = t & 15, mq = t >> 4;
    for (int it = 0; it < 8; it++) {
        int ml = it*16 + mq;
        float4 w = make_float4(s_t[ml*65 + o4*4 + 0], s_t[ml*65 + o4*4 + 1],
                               s_t[ml*65 + o4*4 + 2], s_t[ml*65 + o4*4 + 3]);
        long long idx = ((long long)(l*512 + tsel*256 + msub + ml))*4096 + i*64 + o4*4;
        *(float4*)(dst + idx) = w;
    }
}

// ---- cw -> bf16 hi/lo planes [l][o][i] ----
__global__ void k_cwtrans(const float* cw, float* ws) {
    int gid = blockIdx.x * 256 + threadIdx.x;  // 16384
    ushort* ch = (ushort*)(ws + OFF_CWB);
    ushort* cl = ch + 16384;
    ushort hi, lo; split2(cw[gid], hi, lo);
    ch[gid] = hi; cl[gid] = lo;
}

// ---- p1 transpose -> bf16 hi/lo planes p1t[u(128)][i(64)] ----
__global__ void k_p1trans(const float* p1w, float* ws) {
    int gid = blockIdx.x * 256 + threadIdx.x;  // 8192
    int u = gid >> 6, i = gid & 63;
    ushort* ph = (ushort*)(ws + OFF_P1T);
    ushort hi, lo; split2(p1w[i*128 + u], hi, lo);
    ph[gid] = hi; ph[8192 + gid] = lo;
}

// ---- fused lift + chunk-initial DFT-W:
// h = x@lw+lb (written to h planes + staged transposed in LDS),
// then Y1[kk(32) x c(64)] = F[32x256] @ h[256x64] per (b,hh) row.
__global__ __launch_bounds__(256) void k_liftdftw(const float* x, const float* lw,
                                                   const float* lb, float* ws, int bbase) {
    __shared__ ushort sBhi[64*128];
    __shared__ ushort sBlo[64*128];
    __shared__ float s_lw[192];
    int t = threadIdx.x;
    int bh = blockIdx.x;                  // CB*256
    int lane = t & 63, wid = t >> 6;
    int oc = lane & 15, g = lane >> 4;
    ushort* hH = (ushort*)ws;
    ushort* hL = (ushort*)(ws + OFF_HLO_F);
    const ushort* fh = (const ushort*)(ws + OFF_FWA);
    const ushort* fl = fh + 8192;
    if (t < 192) s_lw[t] = (t < 128) ? lw[t] : lb[t - 128];
    int mt = wid & 1, nt0 = wid >> 1;
    f32x4 acc0 = {0.f,0.f,0.f,0.f}, acc1 = {0.f,0.f,0.f,0.f};
    long long rowbase = (long long)bh * 16384;
    const float* xrow = x + ((long long)bbase*65536 + (long long)bh*256)*2;
    for (int half = 0; half < 2; half++) {
        __syncthreads();   // s_lw ready / previous half's MFMA reads done
        {
            int wl = t & 127;             // w within half
            int w  = half*128 + wl;
            int cr = (t >> 7) * 32;       // this thread's c-range
            float x0 = xrow[w*2], x1 = xrow[w*2 + 1];
            for (int cq = 0; cq < 4; cq++) {
                U8 hiv, lov;
                #pragma unroll
                for (int j = 0; j < 8; j++) {
                    int c = cr + cq*8 + j;
                    float v = x0*s_lw[c] + x1*s_lw[64 + c] + s_lw[128 + c];
                    split2(v, hiv.u[j], lov.u[j]);
                    int key = (((c & 7) ^ ((c >> 3) & 7)) << 3);
                    sBhi[c*128 + (wl ^ key)] = hiv.u[j];
                    sBlo[c*128 + (wl ^ key)] = lov.u[j];
                }
                long long ga = rowbase + (long long)w*64 + cr + cq*8;
                *(uint4*)&hH[ga] = hiv.v;
                *(uint4*)&hL[ga] = lov.v;
            }
        }
        __syncthreads();
        #pragma unroll
        for (int ksl = 0; ksl < 4; ksl++) {
            int gks = half*4 + ksl;
            bf16x8 Ah = *(const bf16x8*)&fh[((mt*8 + gks)*64 + lane)*8];
            bf16x8 Al = *(const bf16x8*)&fl[((mt*8 + gks)*64 + lane)*8];
            int wof = ksl*32 + 8*g;
            #pragma unroll
            for (int q = 0; q < 2; q++) {
                int c = (nt0 + q*2)*16 + oc;
                int key = (((c & 7) ^ ((c >> 3) & 7)) << 3);
                bf16x8 Bh = *(const bf16x8*)&sBhi[c*128 + (wof ^ key)];
                bf16x8 Bl = *(const bf16x8*)&sBlo[c*128 + (wof ^ key)];
                f32x4 a = q ? acc1 : acc0;
                a = __builtin_amdgcn_mfma_f32_16x16x32_bf16(Ah, Bh, a, 0,0,0);
                a = __builtin_amdgcn_mfma_f32_16x16x32_bf16(Al, Bh, a, 0,0,0);
                a = __builtin_amdgcn_mfma_f32_16x16x32_bf16(Ah, Bl, a, 0,0,0);
                if (q) acc1 = a; else acc0 = a;
            }
        }
    }
    int b = bh >> 8, hh = bh & 255;
    #pragma unroll
    for (int q = 0; q < 2; q++) {
        f32x4 a = q ? acc1 : acc0;
        int c = (nt0 + q*2)*16 + oc;
        #pragma unroll
        for (int r = 0; r < 4; r++) {
            int kk = mt*16 + 4*g + r;
            int ky = kk >> 1;
            long long addr = ((long long)(b*16 + ky)*256 + hh)*64 + c;
            ws[((kk & 1) ? OFF_Y1IM : OFF_Y1RE) + addr] = a[r];
        }
    }
}

// ---- DFT along H (fp32 VALU) ----
__global__ __launch_bounds__(256) void k_dfth(float* ws) {
    __shared__ __align__(16) float s_yre[64*32];
    __shared__ __align__(16) float s_yim[64*32];
    __shared__ __align__(16) float s_tw[512];
    int t = threadIdx.x;
    int bk = blockIdx.x;
    int chalf = bk & 1;
    int ky = (bk >> 1) & 15;
    int b = bk >> 5;
    ((float2*)s_tw)[t] = ((const float2*)(ws + OFF_TW))[t];
    int kxi = t & 31;
    int cq = t >> 5;
    int kxa = (kxi < 16) ? kxi : (224 + kxi);
    float accRe[4] = {0.f,0.f,0.f,0.f}, accIm[4] = {0.f,0.f,0.f,0.f};
    const float* yre = ws + OFF_Y1RE + (long long)(b*16 + ky)*(256*64);
    const float* yim = ws + OFF_Y1IM + (long long)(b*16 + ky)*(256*64);
    for (int chunk = 0; chunk < 4; chunk++) {
        __syncthreads();
        for (int j = 0; j < 2; j++) {
            int n = j*256 + t;
            int hl = n >> 3, c4 = n & 7;
            long long soff = (long long)(chunk*64 + hl)*64 + chalf*32 + c4*4;
            ((float4*)s_yre)[hl*8 + c4] = *(const float4*)(yre + soff);
            ((float4*)s_yim)[hl*8 + c4] = *(const float4*)(yim + soff);
        }
        __syncthreads();
        for (int hl = 0; hl < 64; hl++) {
            int h = chunk*64 + hl;
            float2 tw = ((const float2*)s_tw)[(kxa*h) & 255];
            float4 yr = *(const float4*)&s_yre[hl*32 + 4*cq];
            float4 yi = *(const float4*)&s_yim[hl*32 + 4*cq];
            accRe[0] += yr.x*tw.x + yi.x*tw.y;
            accRe[1] += yr.y*tw.x + yi.y*tw.y;
            accRe[2] += yr.z*tw.x + yi.z*tw.y;
            accRe[3] += yr.w*tw.x + yi.w*tw.y;
            accIm[0] += yi.x*tw.x - yr.x*tw.y;
            accIm[1] += yi.y*tw.x - yr.y*tw.y;
            accIm[2] += yi.z*tw.x - yr.z*tw.y;
            accIm[3] += yi.w*tw.x - yr.w*tw.y;
        }
    }
    long long base = ((long long)((b*32 + kxi)*16 + ky))*64 + chalf*32 + 4*cq;
    *(float4*)&ws[OFF_FTRE + base] = make_float4(accRe[0], accRe[1], accRe[2], accRe[3]);
    *(float4*)&ws[OFF_FTIM + base] = make_float4(accIm[0], accIm[1], accIm[2], accIm[3]);
}

// ---- mode mix ----
__global__ __launch_bounds__(256) void k_mix(float* ws, int l) {
    __shared__ __align__(16) float2 s_ft[CB*64];
    int t = threadIdx.x;
    int kk = blockIdx.x;
    int kxi = kk >> 4, ky = kk & 15;
    for (int j = 0; j < 2; j++) {
        int idx = j*256 + t;
        int i = idx & 63, b = idx >> 6;
        long long a = ((long long)(b*32 + kxi)*16 + ky)*64 + i;
        s_ft[b*64 + i] = make_float2(ws[OFF_FTRE + a], ws[OFF_FTIM + a]);
    }
    __syncthreads();
    int o = t & 63, bq = t >> 6;
    const float* wr = ws + OFF_WTRE + (((long long)l*32 + kxi)*16 + ky)*4096;
    const float* wi = ws + OFF_WTIM + (((long long)l*32 + kxi)*16 + ky)*4096;
    float accRe[2] = {0.f,0.f}, accIm[2] = {0.f,0.f};
    #pragma unroll 4
    for (int i = 0; i < 64; i++) {
        float wrv = wr[i*64 + o], wiv = wi[i*64 + o];
        #pragma unroll
        for (int j = 0; j < 2; j++) {
            float2 a = s_ft[(bq*2 + j)*64 + i];
            accRe[j] += a.x*wrv - a.y*wiv;
            accIm[j] += a.x*wiv + a.y*wrv;
        }
    }
    #pragma unroll
    for (int j = 0; j < 2; j++) {
        int b = bq*2 + j;
        long long a = ((long long)(b*32 + kxi)*16 + ky)*64 + o;
        ws[OFF_ORE + a] = accRe[j];
        ws[OFF_OIM + a] = accIm[j];
    }
}

// ---- fused layer (512 threads, 8 waves): IDFT-H(O)->B; conv+IDFT-W MFMA;
//      gelu -> h (+sT); DFT-W -> Y1 ----
__global__ __launch_bounds__(512) void k_layer_out(float* ws, const float* cb, int l, int do_dft) {
    __shared__ __align__(16) ushort sMem[16384];   // 32 KB union
    ushort* sBhi = sMem;          // conv-B 64*104
    ushort* sBlo = sMem + 6656;
    ushort* sAhi = sMem;          // h_old staging 128*64 (swizzled)
    ushort* sAlo = sMem + 8192;
    ushort* sThi = sMem;          // h_new transposed 64*128 (swizzled)
    ushort* sTlo = sMem + 8192;
    int t = threadIdx.x;
    int bh = blockIdx.x;
    int lane = t & 63, wid = t >> 6;          // wid 0..7
    int oc = lane & 15, g = lane >> 4;
    int b = bh >> 8, hh = bh & 255;
    ushort* hH = (ushort*)ws;
    ushort* hL = (ushort*)(ws + OFF_HLO_F);

    // ---- B: g part via fused IDFT-H from O (k=0..31); 2 cols per thread ----
    {
        int ky = t >> 5, o0 = (t & 31) * 2;
        const float* ore = ws + OFF_ORE;
        const float* oim = ws + OFF_OIM;
        const float2* twg = (const float2*)(ws + OFF_TW);
        float gr0=0,gr1=0, gi0=0,gi1=0;
        #pragma unroll 8
        for (int kxi = 0; kxi < 32; kxi++) {
            int kxa = (kxi < 16) ? kxi : (224 + kxi);
            float2 tw = twg[(kxa * hh) & 255];
            long long a = ((long long)((b*32 + kxi)*16 + ky))*64 + o0;
            float2 vr = *(const float2*)(ore + a);
            float2 vi = *(const float2*)(oim + a);
            gr0 += vr.x*tw.x - vi.x*tw.y;  gi0 += vr.x*tw.y + vi.x*tw.x;
            gr1 += vr.y*tw.x - vi.y*tw.y;  gi1 += vr.y*tw.y + vi.y*tw.x;
        }
        float scale = (ky == 0 ? 1.0f : 2.0f) * (1.0f/65536.0f);
        float grs[2] = {gr0,gr1}, gis[2] = {gi0,gi1};
        #pragma unroll
        for (int j = 0; j < 2; j++) {
            ushort h0,l0,h1,l1;
            split2(grs[j]*scale, h0, l0);
            split2(gis[j]*scale, h1, l1);
            int idx = (o0 + j)*104 + 2*ky;
            sBhi[idx] = h0; sBhi[idx+1] = h1;
            sBlo[idx] = l0; sBlo[idx+1] = l1;
        }
    }
    // ---- B: cw part (k=32..95) ----
    {
        const ushort* ch = (const ushort*)(ws + OFF_CWB) + (long long)l*4096;
        const ushort* clo = (const ushort*)(ws + OFF_CWB) + 16384 + (long long)l*4096;
        int n = t;   // 512 threads cover 512 uint4-pairs
        int o = n >> 3, i0 = (n & 7)*8;
        *(uint4*)&sBhi[o*104 + 32 + i0] = *(const uint4*)&ch[o*64 + i0];
        *(uint4*)&sBlo[o*104 + 32 + i0] = *(const uint4*)&clo[o*64 + i0];
    }
    __syncthreads();
    int o = (wid & 3)*16 + oc;
    int wtg = wid >> 2;                        // which half of the wt's
    bf16x8 B_h[3], B_l[3];
    #pragma unroll
    for (int s = 0; s < 3; s++) {
        int kb = 32*s + 8*g;
        B_h[s] = *(bf16x8*)&sBhi[o*104 + kb];
        B_l[s] = *(bf16x8*)&sBlo[o*104 + kb];
    }
    __syncthreads();   // B-frag reads done before sA overwrites the region
    float cbv = cb[o];
    const ushort* twh = (const ushort*)(ws + OFF_TWA);
    const ushort* twl = twh + 8192;
    const ushort* fh = (const ushort*)(ws + OFF_FWA);
    const ushort* fl = fh + 8192;
    long long rowbase = (long long)bh * 16384;
    int mtd = wid & 1, ntd = (wid >> 1) & 3;   // DFT-W tile per wave
    f32x4 accY = {0.f,0.f,0.f,0.f};
    int keyo = ((o & 7) ^ ((o >> 3) & 7)) << 3;

    for (int half = 0; half < 2; half++) {
        // ---- stage h_old ----
        const ushort* srcH = hH + rowbase + half*8192;
        const ushort* srcL = hL + rowbase + half*8192;
        for (int n = t; n < 1024; n += 512) {
            int row = n >> 3, i0 = (n & 7)*8;
            int idx = row*64 + (i0 ^ ((row & 7) << 3));
            *(uint4*)&sAhi[idx] = *(const uint4*)&srcH[row*64 + i0];
            *(uint4*)&sAlo[idx] = *(const uint4*)&srcL[row*64 + i0];
        }
        __syncthreads();
        // ---- conv + IDFT-W MFMA (4 wt per wave) ----
        f32x4 acc[4];
        #pragma unroll
        for (int wt = 0; wt < 4; wt++) {
            int awt = wtg*4 + wt;
            int gwt = half*8 + awt;
            bf16x8 A0h = *(const bf16x8*)&twh[(gwt*64 + lane)*8];
            bf16x8 A0l = *(const bf16x8*)&twl[(gwt*64 + lane)*8];
            int row = awt*16 + oc;
            int base = row*64;
            int sw = (row & 7) << 3;
            bf16x8 A1h = *(bf16x8*)&sAhi[base + ((8*g) ^ sw)];
            bf16x8 A1l = *(bf16x8*)&sAlo[base + ((8*g) ^ sw)];
            bf16x8 A2h = *(bf16x8*)&sAhi[base + ((32 + 8*g) ^ sw)];
            bf16x8 A2l = *(bf16x8*)&sAlo[base + ((32 + 8*g) ^ sw)];
            f32x4 a = {0.f,0.f,0.f,0.f};
            a = __builtin_amdgcn_mfma_f32_16x16x32_bf16(A0h, B_h[0], a, 0,0,0);
            a = __builtin_amdgcn_mfma_f32_16x16x32_bf16(A0l, B_h[0], a, 0,0,0);
            a = __builtin_amdgcn_mfma_f32_16x16x32_bf16(A0h, B_l[0], a, 0,0,0);
            a = __builtin_amdgcn_mfma_f32_16x16x32_bf16(A1h, B_h[1], a, 0,0,0);
            a = __builtin_amdgcn_mfma_f32_16x16x32_bf16(A1l, B_h[1], a, 0,0,0);
            a = __builtin_amdgcn_mfma_f32_16x16x32_bf16(A1h, B_l[1], a, 0,0,0);
            a = __builtin_amdgcn_mfma_f32_16x16x32_bf16(A2h, B_h[2], a, 0,0,0);
            a = __builtin_amdgcn_mfma_f32_16x16x32_bf16(A2l, B_h[2], a, 0,0,0);
            a = __builtin_amdgcn_mfma_f32_16x16x32_bf16(A2h, B_l[2], a, 0,0,0);
            acc[wt] = a;
        }
        __syncthreads();   // sA reads done; sT may overwrite
        // ---- epilogue: gelu, store h, stage transposed h_new for DFT-W ----
        #pragma unroll
        for (int wt = 0; wt < 4; wt++) {
            int awt = wtg*4 + wt;
            U4 hi4, lo4;
            #pragma unroll
            for (int r = 0; r < 4; r++) {
                float v = acc[wt][r] + cbv;
                float gv = GELU(v);
                split2(gv, hi4.u[r], lo4.u[r]);
                long long oaddr = rowbase + (long long)(half*128 + awt*16 + 4*g + r)*64 + o;
                hH[oaddr] = hi4.u[r];
                hL[oaddr] = lo4.u[r];
            }
            if (do_dft) {
                int wl0 = awt*16 + 4*g;
                int tidx = o*128 + (wl0 ^ keyo);
                *(uint2*)&sThi[tidx] = hi4.v;
                *(uint2*)&sTlo[tidx] = lo4.v;
            }
        }
        if (do_dft) {
            __syncthreads();   // sT visible
            #pragma unroll
            for (int ksl = 0; ksl < 4; ksl++) {
                int gks = half*4 + ksl;
                bf16x8 Ah = *(const bf16x8*)&fh[((mtd*8 + gks)*64 + lane)*8];
                bf16x8 Al = *(const bf16x8*)&fl[((mtd*8 + gks)*64 + lane)*8];
                int wof = ksl*32 + 8*g;
                int c = ntd*16 + oc;
                int key = (((c & 7) ^ ((c >> 3) & 7)) << 3);
                bf16x8 Bh = *(const bf16x8*)&sThi[c*128 + (wof ^ key)];
                bf16x8 Bl = *(const bf16x8*)&sTlo[c*128 + (wof ^ key)];
                accY = __builtin_amdgcn_mfma_f32_16x16x32_bf16(Ah, Bh, accY, 0,0,0);
                accY = __builtin_amdgcn_mfma_f32_16x16x32_bf16(Al, Bh, accY, 0,0,0);
                accY = __builtin_amdgcn_mfma_f32_16x16x32_bf16(Ah, Bl, accY, 0,0,0);
            }
        }
        __syncthreads();   // protect region before next half's staging
    }
    if (do_dft) {
        int c = ntd*16 + oc;
        #pragma unroll
        for (int r = 0; r < 4; r++) {
            int kk = mtd*16 + 4*g + r;
            int ky = kk >> 1;
            long long addr = ((long long)(b*16 + ky)*256 + hh)*64 + c;
            ws[((kk & 1) ? OFF_Y1IM : OFF_Y1RE) + addr] = accY[r];
        }
    }
}

// ---- projection via MFMA, 32-row sub-steps, conflict-free s_u ----
__global__ __launch_bounds__(256) void k_proj(float* ws, const float* p1b,
                                              const float* p2w, const float* p2b, float* out) {
    __shared__ ushort sAhi[64*64];
    __shared__ ushort sAlo[64*64];
    __shared__ float s_u[32*132];
    __shared__ float s_p2[256];
    int t = threadIdx.x;
    int bh = blockIdx.x;
    int lane = t & 63, wid = t >> 6;
    int oc = lane & 15, g = lane >> 4;
    s_p2[t] = p2w[t];
    const ushort* hH = (const ushort*)ws;
    const ushort* hL = (const ushort*)(ws + OFF_HLO_F);
    const ushort* ph = (const ushort*)(ws + OFF_P1T);
    const ushort* pl = ph + 8192;
    bf16x8 Bh[2][2], Bl[2][2];
    float p1bv[2];
    #pragma unroll
    for (int q = 0; q < 2; q++) {
        int u = (wid*2 + q)*16 + oc;
        p1bv[q] = p1b[u];
        #pragma unroll
        for (int ks = 0; ks < 2; ks++) {
            Bh[q][ks] = *(const bf16x8*)&ph[u*64 + ks*32 + 8*g];
            Bl[q][ks] = *(const bf16x8*)&pl[u*64 + ks*32 + 8*g];
        }
    }
    float p2b0 = p2b[0], p2b1 = p2b[1];
    long long rowbase = (long long)bh * 16384;
    float* obase = out + (long long)bh * 512;
    for (int qt = 0; qt < 4; qt++) {
        __syncthreads();
        for (int r = 0; r < 2; r++) {
            int n = r*256 + t;
            int row = n >> 3, i0 = (n & 7)*8;
            long long gidx = rowbase + (long long)(qt*64 + row)*64 + i0;
            int idx = row*64 + (i0 ^ ((row & 7) << 3));
            *(uint4*)&sAhi[idx] = *(const uint4*)&hH[gidx];
            *(uint4*)&sAlo[idx] = *(const uint4*)&hL[gidx];
        }
        __syncthreads();
        for (int sub = 0; sub < 2; sub++) {
            #pragma unroll
            for (int mth = 0; mth < 2; mth++) {
                int mt = sub*2 + mth;
                int row = mt*16 + oc;
                int base = row*64, sw = (row & 7) << 3;
                bf16x8 A0h = *(bf16x8*)&sAhi[base + ((8*g) ^ sw)];
                bf16x8 A0l = *(bf16x8*)&sAlo[base + ((8*g) ^ sw)];
                bf16x8 A1h = *(bf16x8*)&sAhi[base + ((32 + 8*g) ^ sw)];
                bf16x8 A1l = *(bf16x8*)&sAlo[base + ((32 + 8*g) ^ sw)];
                #pragma unroll
                for (int q = 0; q < 2; q++) {
                    f32x4 a = {0.f,0.f,0.f,0.f};
                    a = __builtin_amdgcn_mfma_f32_16x16x32_bf16(A0h, Bh[q][0], a, 0,0,0);
                    a = __builtin_amdgcn_mfma_f32_16x16x32_bf16(A0l, Bh[q][0], a, 0,0,0);
                    a = __builtin_amdgcn_mfma_f32_16x16x32_bf16(A0h, Bl[q][0], a, 0,0,0);
                    a = __builtin_amdgcn_mfma_f32_16x16x32_bf16(A1h, Bh[q][1], a, 0,0,0);
                    a = __builtin_amdgcn_mfma_f32_16x16x32_bf16(A1l, Bh[q][1], a, 0,0,0);
                    a = __builtin_amdgcn_mfma_f32_16x16x32_bf16(A1h, Bl[q][1], a, 0,0,0);
                    int ucol = (wid*2 + q)*16 + oc;
                    int uoff = ucol + (ucol >> 5);
                    #pragma unroll
                    for (int r = 0; r < 4; r++) {
                        float v = a[r] + p1bv[q];
                        s_u[(mth*16 + 4*g + r)*132 + uoff] = GELU(v);
                    }
                }
            }
            __syncthreads();
            {
                int wl = t >> 3, co = (t >> 2) & 1, seg = t & 3;
                float s = 0.f;
                #pragma unroll
                for (int u = 0; u < 32; u++)
                    s += s_u[wl*132 + seg*33 + u] * s_p2[(seg*32 + u)*2 + co];
                s += __shfl_xor(s, 1);
                s += __shfl_xor(s, 2);
                if (seg == 0)
                    obase[(qt*64 + sub*32 + wl)*2 + co] = s + (co ? p2b1 : p2b0);
            }
            __syncthreads();
        }
    }
}

extern "C" void kernel_launch(void* const* d_in, const int* in_sizes, int n_in,
                              void* d_out, int out_size, void* d_ws, size_t ws_size,
                              hipStream_t stream) {
    (void)in_sizes; (void)n_in; (void)out_size; (void)ws_size;
    const float* x   = (const float*)d_in[0];
    const float* lw  = (const float*)d_in[1];
    const float* lb  = (const float*)d_in[2];
    const float* w1r = (const float*)d_in[3];
    const float* w1i = (const float*)d_in[4];
    const float* w2r = (const float*)d_in[5];
    const float* w2i = (const float*)d_in[6];
    const float* cw  = (const float*)d_in[7];
    const float* cb  = (const float*)d_in[8];
    const float* p1w = (const float*)d_in[9];
    const float* p1b = (const float*)d_in[10];
    const float* p2w = (const float*)d_in[11];
    const float* p2b = (const float*)d_in[12];
    float* ws  = (float*)d_ws;
    float* out = (float*)d_out;

    k_init_tables<<<dim3(1), dim3(256), 0, stream>>>(ws);
    k_wtrans<<<dim3(2048), dim3(256), 0, stream>>>(w1r, w1i, w2r, w2i, ws);
    k_cwtrans<<<dim3(64), dim3(256), 0, stream>>>(cw, ws);
    k_p1trans<<<dim3(32), dim3(256), 0, stream>>>(p1w, ws);
    for (int chunk = 0; chunk < 16/CB; chunk++) {
        k_liftdftw<<<dim3(CB*256), dim3(256), 0, stream>>>(x, lw, lb, ws, chunk*CB);
        for (int l = 0; l < 4; l++) {
            k_dfth<<<dim3(CB*32), dim3(256), 0, stream>>>(ws);
            k_mix<<<dim3(512), dim3(256), 0, stream>>>(ws, l);
            k_layer_out<<<dim3(CB*256), dim3(512), 0, stream>>>(ws, cb + l*64, l, (l < 3) ? 1 : 0);
        }
        k_proj<<<dim3(CB*256), dim3(256), 0, stream>>>(ws, p1b, p2w, p2b,
                                                       out + (long long)chunk*CB*256*256*2);
    }
}